// Round 1
// baseline (2734.642 us; speedup 1.0000x reference)
//
#include <hip/hip_runtime.h>
#include <hip/hip_bf16.h>
#include <math.h>

// ============================================================================
// RAWTextureDetector pipeline, fp32 end-to-end.
//   conv1(4->32)+lrelu -> conv2(32->16)+lrelu -> conv3(16->8)
//   3x multi-scale box-std maps (k=11,25,49, reflect pad) -> fused map
//   exact quantile (radix-histogram select) -> thresholds -> sigmoid mask
// Batch-chunked through ws (nb batches per chunk picked from ws_size).
// ============================================================================

// ---------------------------------------------------------------------------
// Direct 3x3 conv, zero padding, stride 1. Tile 64x32, 256 threads.
// Each thread: 8 consecutive x pixels x COT output channels (acc in regs).
// Weights indexed block-uniformly (co-group in grid.z) -> scalar loads.
// Input channel slice staged in LDS (padded stride 68 so rows are 16B-aligned).
// ---------------------------------------------------------------------------
template<int CIN, int COUT, int COT, bool LRELU>
__global__ __launch_bounds__(256) void conv3x3_k(
    const float* __restrict__ in,   // [nb, CIN, 512, 512]
    const float* __restrict__ wgt,  // [COUT, CIN, 3, 3]
    const float* __restrict__ bias, // [COUT]
    float* __restrict__ out)        // [nb, COUT, 512, 512]
{
    constexpr int TW = 64, TH = 32, CG = COUT / COT, SW = TW + 4;
    __shared__ float sl[(TH + 2) * SW];

    const int tx  = threadIdx.x & 7;    // 8 x-groups (8 px each)
    const int ty  = threadIdx.x >> 3;   // 32 rows
    const int x0  = blockIdx.x * TW;
    const int y0  = blockIdx.y * TH;
    const int cog = blockIdx.z % CG;
    const int bb  = blockIdx.z / CG;

    const float* inb = in + (size_t)bb * CIN * 512 * 512;

    float acc[COT][8];
#pragma unroll
    for (int j = 0; j < COT; ++j)
#pragma unroll
        for (int p = 0; p < 8; ++p) acc[j][p] = 0.f;

    for (int ci = 0; ci < CIN; ++ci) {
        __syncthreads();   // protect previous iteration's LDS reads
        const float* ip = inb + (size_t)ci * 512 * 512;
        for (int idx = threadIdx.x; idx < (TH + 2) * (TW + 2); idx += 256) {
            int r  = idx / (TW + 2);
            int cc = idx - r * (TW + 2);
            int yy = y0 - 1 + r, xx = x0 - 1 + cc;
            float v = 0.f;
            if ((unsigned)yy < 512u && (unsigned)xx < 512u) v = ip[yy * 512 + xx];
            sl[r * SW + cc] = v;
        }
        __syncthreads();
        const float* wci = wgt + ((size_t)(cog * COT) * CIN + ci) * 9;
#pragma unroll
        for (int dy = 0; dy < 3; ++dy) {
            const float* rowp = &sl[(ty + dy) * SW + tx * 8];  // 16B aligned
            float rr[10];
            float4 a0 = *(const float4*)(rowp);
            float4 a1 = *(const float4*)(rowp + 4);
            float2 a2 = *(const float2*)(rowp + 8);
            rr[0]=a0.x; rr[1]=a0.y; rr[2]=a0.z; rr[3]=a0.w;
            rr[4]=a1.x; rr[5]=a1.y; rr[6]=a1.z; rr[7]=a1.w;
            rr[8]=a2.x; rr[9]=a2.y;
#pragma unroll
            for (int j = 0; j < COT; ++j) {
#pragma unroll
                for (int dx = 0; dx < 3; ++dx) {
                    float w = wci[(size_t)j * CIN * 9 + dy * 3 + dx];
#pragma unroll
                    for (int p = 0; p < 8; ++p)
                        acc[j][p] = fmaf(rr[p + dx], w, acc[j][p]);
                }
            }
        }
    }

    const int y = y0 + ty;
#pragma unroll
    for (int j = 0; j < COT; ++j) {
        int co = cog * COT + j;
        float b = bias[co];
        float* op = out + (((size_t)bb * COUT + co) * 512 + y) * 512 + x0 + tx * 8;
        float v[8];
#pragma unroll
        for (int p = 0; p < 8; ++p) {
            float t = acc[j][p] + b;
            if (LRELU) t = t > 0.f ? t : 0.2f * t;
            v[p] = t;
        }
        ((float4*)op)[0] = make_float4(v[0], v[1], v[2], v[3]);
        ((float4*)op)[1] = make_float4(v[4], v[5], v[6], v[7]);
    }
}

// ---------------------------------------------------------------------------
// Multi-scale std map + fusion. One block per (row y, batch). 256 threads,
// each owns columns x = 2t, 2t+1 (float2 loads).
// Vertical reflect-padded window sums via nested rings over 49 mirrored rows;
// horizontal via in-LDS prefix scan + range diff with mirror terms.
// ---------------------------------------------------------------------------
__device__ __forceinline__ float2 f2add(float2 a, float2 b) {
    return make_float2(a.x + b.x, a.y + b.y);
}

__global__ __launch_bounds__(256) void stdmap_k(
    const float* __restrict__ f,    // [nb, 8, 512, 512]
    const float* __restrict__ fw,   // fusion_w [3]
    const float* __restrict__ fbp,  // fusion_b [1]
    float* __restrict__ fused,      // [8, 512, 512] (global), offset by b0
    int b0)
{
    const int y    = blockIdx.x;
    const int bb   = blockIdx.y;
    const int t    = threadIdx.x;
    const int lane = t & 63, wid = t >> 6;

    __shared__ float Sf[513], Sq[513];
    __shared__ float2 wt[4];

    float smacc[3][2] = {{0.f,0.f},{0.f,0.f},{0.f,0.f}};

    for (int c = 0; c < 8; ++c) {
        const float* base = f + ((size_t)bb * 8 + c) * 512 * 512;
        float2 sf[3] = {{0.f,0.f},{0.f,0.f},{0.f,0.f}};  // ring sums of f
        float2 sq[3] = {{0.f,0.f},{0.f,0.f},{0.f,0.f}};  // ring sums of f^2
#pragma unroll
        for (int dy = -24; dy <= 24; ++dy) {
            int row = y + dy;
            row = row < 0 ? -row : (row > 511 ? 1022 - row : row);  // reflect
            float2 v  = ((const float2*)(base + (size_t)row * 512))[t];
            float2 vq = make_float2(v.x * v.x, v.y * v.y);
            int ad = dy < 0 ? -dy : dy;
            int ring = ad <= 5 ? 0 : (ad <= 12 ? 1 : 2);
            sf[ring] = f2add(sf[ring], v);
            sq[ring] = f2add(sq[ring], vq);
        }
        sf[1] = f2add(sf[1], sf[0]); sq[1] = f2add(sq[1], sq[0]);
        sf[2] = f2add(sf[2], sf[1]); sq[2] = f2add(sq[2], sq[1]);

        const int   RAD[3] = {5, 12, 24};
        const float INV[3] = {1.f/121.f, 1.f/625.f, 1.f/2401.f};
#pragma unroll
        for (int sc = 0; sc < 3; ++sc) {
            // block-wide inclusive scan over 512 columns of (vf, vq)
            float2 e0   = make_float2(sf[sc].x, sq[sc].x);  // x = 2t
            float2 e1   = make_float2(sf[sc].y, sq[sc].y);  // x = 2t+1
            float2 pair = f2add(e0, e1);
            float2 inc  = pair;
#pragma unroll
            for (int off = 1; off < 64; off <<= 1) {
                float2 up;
                up.x = __shfl_up(inc.x, (unsigned)off, 64);
                up.y = __shfl_up(inc.y, (unsigned)off, 64);
                if (lane >= off) inc = f2add(inc, up);
            }
            if (lane == 63) wt[wid] = inc;
            __syncthreads();
            float2 wpre = make_float2(0.f, 0.f);
#pragma unroll
            for (int w = 0; w < 4; ++w)
                if (w < wid) wpre = f2add(wpre, wt[w]);
            float exf = wpre.x + inc.x - pair.x;   // exclusive prefix (f)
            float exq = wpre.y + inc.y - pair.y;   // exclusive prefix (f^2)
            Sf[2*t+1] = exf + e0.x;           Sq[2*t+1] = exq + e0.y;
            Sf[2*t+2] = exf + e0.x + e1.x;    Sq[2*t+2] = exq + e0.y + e1.y;
            if (t == 0) { Sf[0] = 0.f; Sq[0] = 0.f; }
            __syncthreads();

            const int r = RAD[sc];
#pragma unroll
            for (int slot = 0; slot < 2; ++slot) {
                int xx = 2*t + slot;
                int lo = xx - r, hi = xx + r;
                int loc = lo < 0 ? 0 : lo;
                int hic = hi > 511 ? 511 : hi;
                float wfv = Sf[hic + 1] - Sf[loc];
                float wqv = Sq[hic + 1] - Sq[loc];
                if (lo < 0)   { wfv += Sf[r - xx + 1] - Sf[1];
                                wqv += Sq[r - xx + 1] - Sq[1]; }
                if (hi > 511) { wfv += Sf[511] - Sf[1022 - xx - r];
                                wqv += Sq[511] - Sq[1022 - xx - r]; }
                float m   = wfv * INV[sc];
                float m2  = wqv * INV[sc];
                float var = m2 - m * m;
                var = var > 1e-6f ? var : 1e-6f;
                smacc[sc][slot] += sqrtf(var);
            }
            __syncthreads();   // S buffers reused next iteration
        }
    }

    float w0 = fw[0], w1 = fw[1], w2 = fw[2], b = fbp[0];
    float o[2];
#pragma unroll
    for (int slot = 0; slot < 2; ++slot) {
        float m0 = powf(smacc[0][slot] * 0.125f, 0.8f);
        float m1 = powf(smacc[1][slot] * 0.125f, 0.8f);
        float m2 = powf(smacc[2][slot] * 0.125f, 0.8f);
        float fv = w0 * m0 + w1 * m1 + w2 * m2 + b;
        o[slot] = fv > 0.f ? fv : 0.f;
    }
    ((float2*)(fused + ((size_t)(b0 + bb) * 512 + y) * 512))[t] = make_float2(o[0], o[1]);
}

// ---------------------------------------------------------------------------
// Per-(b,c) plane std of x with ddof=1 (fp64 accumulation).
// channel_std = softmax(cw)_c * std  (scalar multiple), handled in finalize.
// ---------------------------------------------------------------------------
__global__ __launch_bounds__(256) void plane_std_k(
    const float* __restrict__ x, float* __restrict__ stds)
{
    const int plane = blockIdx.x;   // b*4 + c, 32 planes
    const float* p = x + (size_t)plane * 262144;
    double s = 0.0, s2 = 0.0;
    for (int i = threadIdx.x; i < 262144; i += 256) {
        float v = p[i];
        s  += (double)v;
        s2 += (double)v * (double)v;
    }
    __shared__ double ls[256], ls2[256];
    ls[threadIdx.x] = s; ls2[threadIdx.x] = s2;
    __syncthreads();
    for (int off = 128; off > 0; off >>= 1) {
        if (threadIdx.x < off) {
            ls[threadIdx.x]  += ls[threadIdx.x + off];
            ls2[threadIdx.x] += ls2[threadIdx.x + off];
        }
        __syncthreads();
    }
    if (threadIdx.x == 0) {
        const double N = 262144.0;
        double var = (ls2[0] - ls[0] * ls[0] / N) / (N - 1.0);
        stds[plane] = (float)sqrt(var > 0.0 ? var : 0.0);
    }
}

// ---------------------------------------------------------------------------
// Exact quantile via 3-level radix histogram (12+12+8 bits) on the uint
// interpretation of the (non-negative) fused values.
// ---------------------------------------------------------------------------
__global__ __launch_bounds__(256) void hist1_k(
    const float* __restrict__ fused, unsigned* __restrict__ h)
{
    __shared__ unsigned lh[4096];
    for (int i = threadIdx.x; i < 4096; i += 256) lh[i] = 0u;
    __syncthreads();
    const int base = blockIdx.x * 2048;
    for (int i = threadIdx.x; i < 2048; i += 256) {
        unsigned bits = __float_as_uint(fused[base + i]);
        atomicAdd(&lh[bits >> 20], 1u);
    }
    __syncthreads();
    for (int i = threadIdx.x; i < 4096; i += 256) {
        unsigned c = lh[i];
        if (c) atomicAdd(&h[i], c);
    }
}

__global__ void select1_k(const unsigned* __restrict__ h,
                          unsigned* __restrict__ pfx, unsigned* __restrict__ rem)
{
    if (threadIdx.x < 4) {
        // order-stat ranks for q25/q75 linear interp, N = 2097152
        const unsigned targets[4] = {524287u, 524288u, 1572863u, 1572864u};
        unsigned R = targets[threadIdx.x];
        unsigned cum = 0;
        for (int bin = 0; bin < 4096; ++bin) {
            unsigned c = h[bin];
            if (cum + c > R) {
                pfx[threadIdx.x] = (unsigned)bin << 20;
                rem[threadIdx.x] = R - cum;
                return;
            }
            cum += c;
        }
        pfx[threadIdx.x] = 0xFFFu << 20; rem[threadIdx.x] = 0u;
    }
}

__global__ __launch_bounds__(256) void hist2_k(
    const float* __restrict__ fused, const unsigned* __restrict__ pfx,
    unsigned* __restrict__ h2)
{
    const int i = blockIdx.x * 256 + threadIdx.x;
    unsigned bits = __float_as_uint(fused[i]);
    unsigned top = bits >> 20;
#pragma unroll
    for (int tt = 0; tt < 4; ++tt)
        if (top == (pfx[tt] >> 20))
            atomicAdd(&h2[tt * 4096 + ((bits >> 8) & 0xFFFu)], 1u);
}

__global__ void select2_k(const unsigned* __restrict__ h2,
                          unsigned* __restrict__ pfx, unsigned* __restrict__ rem)
{
    if (threadIdx.x < 4) {
        unsigned R = rem[threadIdx.x];
        const unsigned* h = h2 + threadIdx.x * 4096;
        unsigned cum = 0;
        for (int bin = 0; bin < 4096; ++bin) {
            unsigned c = h[bin];
            if (cum + c > R) {
                pfx[threadIdx.x] |= (unsigned)bin << 8;
                rem[threadIdx.x] = R - cum;
                return;
            }
            cum += c;
        }
    }
}

__global__ __launch_bounds__(256) void hist3_k(
    const float* __restrict__ fused, const unsigned* __restrict__ pfx,
    unsigned* __restrict__ h3)
{
    const int i = blockIdx.x * 256 + threadIdx.x;
    unsigned bits = __float_as_uint(fused[i]);
#pragma unroll
    for (int tt = 0; tt < 4; ++tt)
        if ((bits >> 8) == (pfx[tt] >> 8))
            atomicAdd(&h3[tt * 256 + (bits & 0xFFu)], 1u);
}

__device__ __forceinline__ float clampf(float v, float lo, float hi) {
    return v < lo ? lo : (v > hi ? hi : v);
}

// select level 3 + all scalar threshold math -> lower[32], upper[32]
__global__ void finalize_k(const unsigned* __restrict__ h3,
                           const unsigned* __restrict__ pfx,
                           const unsigned* __restrict__ rem,
                           const float* __restrict__ stds,
                           const float* __restrict__ cw,
                           float* __restrict__ lu)
{
    if (threadIdx.x != 0) return;
    float vals[4];
    for (int tt = 0; tt < 4; ++tt) {
        unsigned R = rem[tt];
        const unsigned* h = h3 + tt * 256;
        unsigned cum = 0, byte = 255u;
        for (int bin = 0; bin < 256; ++bin) {
            unsigned c = h[bin];
            if (cum + c > R) { byte = (unsigned)bin; break; }
            cum += c;
        }
        vals[tt] = __uint_as_float(pfx[tt] | byte);
    }
    float q25 = vals[0] + 0.75f * (vals[1] - vals[0]);
    float q75 = vals[2] + 0.25f * (vals[3] - vals[2]);
    float iqr = q75 - q25;
    if (iqr < 1e-5f) iqr = 0.05f;
    float lo0 = q25 - 0.5f * iqr, up0 = q75 + 0.5f * iqr;

    // softmax over channel_weights (4)
    float mx = cw[0];
    for (int c = 1; c < 4; ++c) mx = cw[c] > mx ? cw[c] : mx;
    float e[4], se = 0.f;
    for (int c = 0; c < 4; ++c) { e[c] = expf(cw[c] - mx); se += e[c]; }

    float l[32], u[32], mind = 1e30f;
    for (int p = 0; p < 32; ++p) {
        float sd = stds[p];
        int c = p & 3;
        float gf = clampf(sd * 5.f, 0.5f, 2.f);
        float cf = clampf(sd * (e[c] / se) * 2.f, 0.8f, 1.2f);
        l[p] = lo0 * gf * cf;
        u[p] = up0 * gf * cf;
        float d = fabsf(u[p] - l[p]);
        if (d < mind) mind = d;
    }
    bool deg = mind < 1e-5f;
    for (int p = 0; p < 32; ++p) {
        float L = l[p], U = u[p];
        if (deg) { float m = 0.5f * (L + U); L = m - 0.05f; U = m + 0.05f; }
        lu[p] = L; lu[32 + p] = U;
    }
}

__global__ __launch_bounds__(256) void mask_k(
    const float* __restrict__ fused, const float* __restrict__ lu,
    float* __restrict__ out)
{
    const int b = blockIdx.y;
    const int i = blockIdx.x * 256 + threadIdx.x;
    float fv = fused[(size_t)b * 262144 + i];
    float s = 0.f;
#pragma unroll
    for (int c = 0; c < 4; ++c) {
        float L = lu[b * 4 + c], U = lu[32 + b * 4 + c];
        float d = U - L; d = d > 1e-5f ? d : 1e-5f;
        float n = (fv - L) / d;
        n = n < 0.f ? 0.f : (n > 1.f ? 1.f : n);
        s += 1.f / (1.f + expf(3.f - 6.f * n));
    }
    out[(size_t)b * 262144 + i] = 0.25f * s;
}

// ---------------------------------------------------------------------------
extern "C" void kernel_launch(void* const* d_in, const int* in_sizes, int n_in,
                              void* d_out, int out_size, void* d_ws, size_t ws_size,
                              hipStream_t stream)
{
    const float* x   = (const float*)d_in[0];
    const float* c1w = (const float*)d_in[1];
    const float* c1b = (const float*)d_in[2];
    const float* c2w = (const float*)d_in[3];
    const float* c2b = (const float*)d_in[4];
    const float* c3w = (const float*)d_in[5];
    const float* c3b = (const float*)d_in[6];
    const float* fw  = (const float*)d_in[7];
    const float* fb  = (const float*)d_in[8];
    const float* cwt = (const float*)d_in[9];
    float* out = (float*)d_out;
    char* ws = (char*)d_ws;

    const size_t PLANE = 512 * 512;

    // ws layout: fused | stds | lu | pfx | rem | h1|h2|h3 | chunk bufs
    float* fused = (float*)ws;
    size_t off = 8 * PLANE * sizeof(float);
    float* stds = (float*)(ws + off); off += 32 * 4;
    float* lu   = (float*)(ws + off); off += 64 * 4;
    off = (off + 255) & ~(size_t)255;
    unsigned* pfx = (unsigned*)(ws + off); off += 16;
    unsigned* rem = (unsigned*)(ws + off); off += 16;
    off = (off + 255) & ~(size_t)255;
    unsigned* h1 = (unsigned*)(ws + off); off += 4096 * 4;
    unsigned* h2 = (unsigned*)(ws + off); off += 4 * 4096 * 4;
    unsigned* h3 = (unsigned*)(ws + off); off += 4 * 256 * 4;
    off = (off + 1023) & ~(size_t)1023;

    // chunk buffers: f1(32ch) + f2(16ch) + f(8ch) per batch = 56 planes
    const size_t perb = 56 * PLANE * sizeof(float);
    int nb = 8;
    while (nb > 1 && off + (size_t)nb * perb > ws_size) nb >>= 1;
    float* f1  = (float*)(ws + off);
    float* f2  = f1 + (size_t)nb * 32 * PLANE;
    float* fch = f2 + (size_t)nb * 16 * PLANE;

    hipLaunchKernelGGL(plane_std_k, dim3(32), dim3(256), 0, stream, x, stds);

    for (int b0 = 0; b0 < 8; b0 += nb) {
        const float* xc = x + (size_t)b0 * 4 * PLANE;
        hipLaunchKernelGGL((conv3x3_k<4, 32, 8, true>),   dim3(8, 16, nb * 4),
                           dim3(256), 0, stream, xc, c1w, c1b, f1);
        hipLaunchKernelGGL((conv3x3_k<32, 16, 16, true>), dim3(8, 16, nb),
                           dim3(256), 0, stream, f1, c2w, c2b, f2);
        hipLaunchKernelGGL((conv3x3_k<16, 8, 8, false>),  dim3(8, 16, nb),
                           dim3(256), 0, stream, f2, c3w, c3b, fch);
        hipLaunchKernelGGL(stdmap_k, dim3(512, nb), dim3(256), 0, stream,
                           fch, fw, fb, fused, b0);
    }

    hipMemsetAsync(h1, 0, (4096 + 4 * 4096 + 4 * 256) * 4, stream);
    hipLaunchKernelGGL(hist1_k,   dim3(1024), dim3(256), 0, stream, fused, h1);
    hipLaunchKernelGGL(select1_k, dim3(1),    dim3(64),  0, stream, h1, pfx, rem);
    hipLaunchKernelGGL(hist2_k,   dim3(8192), dim3(256), 0, stream, fused, pfx, h2);
    hipLaunchKernelGGL(select2_k, dim3(1),    dim3(64),  0, stream, h2, pfx, rem);
    hipLaunchKernelGGL(hist3_k,   dim3(8192), dim3(256), 0, stream, fused, pfx, h3);
    hipLaunchKernelGGL(finalize_k, dim3(1),   dim3(64),  0, stream,
                       h3, pfx, rem, stds, cwt, lu);
    hipLaunchKernelGGL(mask_k, dim3(1024, 8), dim3(256), 0, stream, fused, lu, out);
}

// Round 2
// 2297.762 us; speedup vs baseline: 1.1901x; 1.1901x over previous
//
#include <hip/hip_runtime.h>
#include <hip/hip_bf16.h>
#include <math.h>

// ============================================================================
// RAWTextureDetector pipeline, fp32 end-to-end.
//   conv1(4->32)+lrelu -> conv2(32->16)+lrelu -> conv3(16->8)
//   3x multi-scale box-std maps (k=11,25,49, reflect pad) -> fused map
//   exact quantile (radix-histogram select) -> thresholds -> sigmoid mask
// Batch-chunked through ws (nb batches per chunk picked from ws_size).
// R2: plane_std rewritten as two-stage full-chip reduction (was 433us at
//     1.3% occupancy / 38 GB/s).
// ============================================================================

// ---------------------------------------------------------------------------
// Direct 3x3 conv, zero padding, stride 1. Tile 64x32, 256 threads.
// Each thread: 8 consecutive x pixels x COT output channels (acc in regs).
// Weights indexed block-uniformly (co-group in grid.z) -> scalar loads.
// Input channel slice staged in LDS (padded stride 68 so rows are 16B-aligned).
// ---------------------------------------------------------------------------
template<int CIN, int COUT, int COT, bool LRELU>
__global__ __launch_bounds__(256) void conv3x3_k(
    const float* __restrict__ in,   // [nb, CIN, 512, 512]
    const float* __restrict__ wgt,  // [COUT, CIN, 3, 3]
    const float* __restrict__ bias, // [COUT]
    float* __restrict__ out)        // [nb, COUT, 512, 512]
{
    constexpr int TW = 64, TH = 32, CG = COUT / COT, SW = TW + 4;
    __shared__ float sl[(TH + 2) * SW];

    const int tx  = threadIdx.x & 7;    // 8 x-groups (8 px each)
    const int ty  = threadIdx.x >> 3;   // 32 rows
    const int x0  = blockIdx.x * TW;
    const int y0  = blockIdx.y * TH;
    const int cog = blockIdx.z % CG;
    const int bb  = blockIdx.z / CG;

    const float* inb = in + (size_t)bb * CIN * 512 * 512;

    float acc[COT][8];
#pragma unroll
    for (int j = 0; j < COT; ++j)
#pragma unroll
        for (int p = 0; p < 8; ++p) acc[j][p] = 0.f;

    for (int ci = 0; ci < CIN; ++ci) {
        __syncthreads();   // protect previous iteration's LDS reads
        const float* ip = inb + (size_t)ci * 512 * 512;
        for (int idx = threadIdx.x; idx < (TH + 2) * (TW + 2); idx += 256) {
            int r  = idx / (TW + 2);
            int cc = idx - r * (TW + 2);
            int yy = y0 - 1 + r, xx = x0 - 1 + cc;
            float v = 0.f;
            if ((unsigned)yy < 512u && (unsigned)xx < 512u) v = ip[yy * 512 + xx];
            sl[r * SW + cc] = v;
        }
        __syncthreads();
        const float* wci = wgt + ((size_t)(cog * COT) * CIN + ci) * 9;
#pragma unroll
        for (int dy = 0; dy < 3; ++dy) {
            const float* rowp = &sl[(ty + dy) * SW + tx * 8];  // 16B aligned
            float rr[10];
            float4 a0 = *(const float4*)(rowp);
            float4 a1 = *(const float4*)(rowp + 4);
            float2 a2 = *(const float2*)(rowp + 8);
            rr[0]=a0.x; rr[1]=a0.y; rr[2]=a0.z; rr[3]=a0.w;
            rr[4]=a1.x; rr[5]=a1.y; rr[6]=a1.z; rr[7]=a1.w;
            rr[8]=a2.x; rr[9]=a2.y;
#pragma unroll
            for (int j = 0; j < COT; ++j) {
#pragma unroll
                for (int dx = 0; dx < 3; ++dx) {
                    float w = wci[(size_t)j * CIN * 9 + dy * 3 + dx];
#pragma unroll
                    for (int p = 0; p < 8; ++p)
                        acc[j][p] = fmaf(rr[p + dx], w, acc[j][p]);
                }
            }
        }
    }

    const int y = y0 + ty;
#pragma unroll
    for (int j = 0; j < COT; ++j) {
        int co = cog * COT + j;
        float b = bias[co];
        float* op = out + (((size_t)bb * COUT + co) * 512 + y) * 512 + x0 + tx * 8;
        float v[8];
#pragma unroll
        for (int p = 0; p < 8; ++p) {
            float t = acc[j][p] + b;
            if (LRELU) t = t > 0.f ? t : 0.2f * t;
            v[p] = t;
        }
        ((float4*)op)[0] = make_float4(v[0], v[1], v[2], v[3]);
        ((float4*)op)[1] = make_float4(v[4], v[5], v[6], v[7]);
    }
}

// ---------------------------------------------------------------------------
// Multi-scale std map + fusion. One block per (row y, batch). 256 threads,
// each owns columns x = 2t, 2t+1 (float2 loads).
// Vertical reflect-padded window sums via nested rings over 49 mirrored rows;
// horizontal via in-LDS prefix scan + range diff with mirror terms.
// ---------------------------------------------------------------------------
__device__ __forceinline__ float2 f2add(float2 a, float2 b) {
    return make_float2(a.x + b.x, a.y + b.y);
}

__global__ __launch_bounds__(256) void stdmap_k(
    const float* __restrict__ f,    // [nb, 8, 512, 512]
    const float* __restrict__ fw,   // fusion_w [3]
    const float* __restrict__ fbp,  // fusion_b [1]
    float* __restrict__ fused,      // [8, 512, 512] (global), offset by b0
    int b0)
{
    const int y    = blockIdx.x;
    const int bb   = blockIdx.y;
    const int t    = threadIdx.x;
    const int lane = t & 63, wid = t >> 6;

    __shared__ float Sf[513], Sq[513];
    __shared__ float2 wt[4];

    float smacc[3][2] = {{0.f,0.f},{0.f,0.f},{0.f,0.f}};

    for (int c = 0; c < 8; ++c) {
        const float* base = f + ((size_t)bb * 8 + c) * 512 * 512;
        float2 sf[3] = {{0.f,0.f},{0.f,0.f},{0.f,0.f}};  // ring sums of f
        float2 sq[3] = {{0.f,0.f},{0.f,0.f},{0.f,0.f}};  // ring sums of f^2
#pragma unroll
        for (int dy = -24; dy <= 24; ++dy) {
            int row = y + dy;
            row = row < 0 ? -row : (row > 511 ? 1022 - row : row);  // reflect
            float2 v  = ((const float2*)(base + (size_t)row * 512))[t];
            float2 vq = make_float2(v.x * v.x, v.y * v.y);
            int ad = dy < 0 ? -dy : dy;
            int ring = ad <= 5 ? 0 : (ad <= 12 ? 1 : 2);
            sf[ring] = f2add(sf[ring], v);
            sq[ring] = f2add(sq[ring], vq);
        }
        sf[1] = f2add(sf[1], sf[0]); sq[1] = f2add(sq[1], sq[0]);
        sf[2] = f2add(sf[2], sf[1]); sq[2] = f2add(sq[2], sq[1]);

        const int   RAD[3] = {5, 12, 24};
        const float INV[3] = {1.f/121.f, 1.f/625.f, 1.f/2401.f};
#pragma unroll
        for (int sc = 0; sc < 3; ++sc) {
            // block-wide inclusive scan over 512 columns of (vf, vq)
            float2 e0   = make_float2(sf[sc].x, sq[sc].x);  // x = 2t
            float2 e1   = make_float2(sf[sc].y, sq[sc].y);  // x = 2t+1
            float2 pair = f2add(e0, e1);
            float2 inc  = pair;
#pragma unroll
            for (int off = 1; off < 64; off <<= 1) {
                float2 up;
                up.x = __shfl_up(inc.x, (unsigned)off, 64);
                up.y = __shfl_up(inc.y, (unsigned)off, 64);
                if (lane >= off) inc = f2add(inc, up);
            }
            if (lane == 63) wt[wid] = inc;
            __syncthreads();
            float2 wpre = make_float2(0.f, 0.f);
#pragma unroll
            for (int w = 0; w < 4; ++w)
                if (w < wid) wpre = f2add(wpre, wt[w]);
            float exf = wpre.x + inc.x - pair.x;   // exclusive prefix (f)
            float exq = wpre.y + inc.y - pair.y;   // exclusive prefix (f^2)
            Sf[2*t+1] = exf + e0.x;           Sq[2*t+1] = exq + e0.y;
            Sf[2*t+2] = exf + e0.x + e1.x;    Sq[2*t+2] = exq + e0.y + e1.y;
            if (t == 0) { Sf[0] = 0.f; Sq[0] = 0.f; }
            __syncthreads();

            const int r = RAD[sc];
#pragma unroll
            for (int slot = 0; slot < 2; ++slot) {
                int xx = 2*t + slot;
                int lo = xx - r, hi = xx + r;
                int loc = lo < 0 ? 0 : lo;
                int hic = hi > 511 ? 511 : hi;
                float wfv = Sf[hic + 1] - Sf[loc];
                float wqv = Sq[hic + 1] - Sq[loc];
                if (lo < 0)   { wfv += Sf[r - xx + 1] - Sf[1];
                                wqv += Sq[r - xx + 1] - Sq[1]; }
                if (hi > 511) { wfv += Sf[511] - Sf[1022 - xx - r];
                                wqv += Sq[511] - Sq[1022 - xx - r]; }
                float m   = wfv * INV[sc];
                float m2  = wqv * INV[sc];
                float var = m2 - m * m;
                var = var > 1e-6f ? var : 1e-6f;
                smacc[sc][slot] += sqrtf(var);
            }
            __syncthreads();   // S buffers reused next iteration
        }
    }

    float w0 = fw[0], w1 = fw[1], w2 = fw[2], b = fbp[0];
    float o[2];
#pragma unroll
    for (int slot = 0; slot < 2; ++slot) {
        float m0 = powf(smacc[0][slot] * 0.125f, 0.8f);
        float m1 = powf(smacc[1][slot] * 0.125f, 0.8f);
        float m2 = powf(smacc[2][slot] * 0.125f, 0.8f);
        float fv = w0 * m0 + w1 * m1 + w2 * m2 + b;
        o[slot] = fv > 0.f ? fv : 0.f;
    }
    ((float2*)(fused + ((size_t)(b0 + bb) * 512 + y) * 512))[t] = make_float2(o[0], o[1]);
}

// ---------------------------------------------------------------------------
// Per-(b,c) plane std of x, ddof=1. Two-stage deterministic reduction.
// Stage 1: 32 planes x 32 blocks, each block reduces 8192 elems (fp64 acc),
//          writes (s, s2) to partials. Stage 2: 32 threads finalize.
// ---------------------------------------------------------------------------
__global__ __launch_bounds__(256) void plane_std_part_k(
    const float* __restrict__ x, double* __restrict__ part) // [32][32][2]
{
    const int plane = blockIdx.x >> 5;       // 0..31
    const int blk   = blockIdx.x & 31;       // 0..31
    const float* p = x + (size_t)plane * 262144 + (size_t)blk * 8192;
    double s = 0.0, s2 = 0.0;
    // 8192 elems / 256 threads = 32 each; float4 loads, 8 iters
    for (int i = threadIdx.x; i < 2048; i += 256) {
        float4 v = ((const float4*)p)[i];
        s  += (double)v.x + (double)v.y + (double)v.z + (double)v.w;
        s2 += (double)v.x * v.x + (double)v.y * v.y
            + (double)v.z * v.z + (double)v.w * v.w;
    }
    __shared__ double ls[256], ls2[256];
    ls[threadIdx.x] = s; ls2[threadIdx.x] = s2;
    __syncthreads();
    for (int off = 128; off > 0; off >>= 1) {
        if (threadIdx.x < off) {
            ls[threadIdx.x]  += ls[threadIdx.x + off];
            ls2[threadIdx.x] += ls2[threadIdx.x + off];
        }
        __syncthreads();
    }
    if (threadIdx.x == 0) {
        part[2 * blockIdx.x]     = ls[0];
        part[2 * blockIdx.x + 1] = ls2[0];
    }
}

__global__ void plane_std_fin_k(const double* __restrict__ part,
                                float* __restrict__ stds)
{
    const int plane = threadIdx.x;
    if (plane >= 32) return;
    double s = 0.0, s2 = 0.0;
    for (int b = 0; b < 32; ++b) {
        s  += part[2 * (plane * 32 + b)];
        s2 += part[2 * (plane * 32 + b) + 1];
    }
    const double N = 262144.0;
    double var = (s2 - s * s / N) / (N - 1.0);
    stds[plane] = (float)sqrt(var > 0.0 ? var : 0.0);
}

// ---------------------------------------------------------------------------
// Exact quantile via 3-level radix histogram (12+12+8 bits) on the uint
// interpretation of the (non-negative) fused values.
// ---------------------------------------------------------------------------
__global__ __launch_bounds__(256) void hist1_k(
    const float* __restrict__ fused, unsigned* __restrict__ h)
{
    __shared__ unsigned lh[4096];
    for (int i = threadIdx.x; i < 4096; i += 256) lh[i] = 0u;
    __syncthreads();
    const int base = blockIdx.x * 2048;
    for (int i = threadIdx.x; i < 2048; i += 256) {
        unsigned bits = __float_as_uint(fused[base + i]);
        atomicAdd(&lh[bits >> 20], 1u);
    }
    __syncthreads();
    for (int i = threadIdx.x; i < 4096; i += 256) {
        unsigned c = lh[i];
        if (c) atomicAdd(&h[i], c);
    }
}

__global__ void select1_k(const unsigned* __restrict__ h,
                          unsigned* __restrict__ pfx, unsigned* __restrict__ rem)
{
    if (threadIdx.x < 4) {
        // order-stat ranks for q25/q75 linear interp, N = 2097152
        const unsigned targets[4] = {524287u, 524288u, 1572863u, 1572864u};
        unsigned R = targets[threadIdx.x];
        unsigned cum = 0;
        for (int bin = 0; bin < 4096; ++bin) {
            unsigned c = h[bin];
            if (cum + c > R) {
                pfx[threadIdx.x] = (unsigned)bin << 20;
                rem[threadIdx.x] = R - cum;
                return;
            }
            cum += c;
        }
        pfx[threadIdx.x] = 0xFFFu << 20; rem[threadIdx.x] = 0u;
    }
}

__global__ __launch_bounds__(256) void hist2_k(
    const float* __restrict__ fused, const unsigned* __restrict__ pfx,
    unsigned* __restrict__ h2)
{
    const int i = blockIdx.x * 256 + threadIdx.x;
    unsigned bits = __float_as_uint(fused[i]);
    unsigned top = bits >> 20;
#pragma unroll
    for (int tt = 0; tt < 4; ++tt)
        if (top == (pfx[tt] >> 20))
            atomicAdd(&h2[tt * 4096 + ((bits >> 8) & 0xFFFu)], 1u);
}

__global__ void select2_k(const unsigned* __restrict__ h2,
                          unsigned* __restrict__ pfx, unsigned* __restrict__ rem)
{
    if (threadIdx.x < 4) {
        unsigned R = rem[threadIdx.x];
        const unsigned* h = h2 + threadIdx.x * 4096;
        unsigned cum = 0;
        for (int bin = 0; bin < 4096; ++bin) {
            unsigned c = h[bin];
            if (cum + c > R) {
                pfx[threadIdx.x] |= (unsigned)bin << 8;
                rem[threadIdx.x] = R - cum;
                return;
            }
            cum += c;
        }
    }
}

__global__ __launch_bounds__(256) void hist3_k(
    const float* __restrict__ fused, const unsigned* __restrict__ pfx,
    unsigned* __restrict__ h3)
{
    const int i = blockIdx.x * 256 + threadIdx.x;
    unsigned bits = __float_as_uint(fused[i]);
#pragma unroll
    for (int tt = 0; tt < 4; ++tt)
        if ((bits >> 8) == (pfx[tt] >> 8))
            atomicAdd(&h3[tt * 256 + (bits & 0xFFu)], 1u);
}

__device__ __forceinline__ float clampf(float v, float lo, float hi) {
    return v < lo ? lo : (v > hi ? hi : v);
}

// select level 3 + all scalar threshold math -> lower[32], upper[32]
__global__ void finalize_k(const unsigned* __restrict__ h3,
                           const unsigned* __restrict__ pfx,
                           const unsigned* __restrict__ rem,
                           const float* __restrict__ stds,
                           const float* __restrict__ cw,
                           float* __restrict__ lu)
{
    if (threadIdx.x != 0) return;
    float vals[4];
    for (int tt = 0; tt < 4; ++tt) {
        unsigned R = rem[tt];
        const unsigned* h = h3 + tt * 256;
        unsigned cum = 0, byte = 255u;
        for (int bin = 0; bin < 256; ++bin) {
            unsigned c = h[bin];
            if (cum + c > R) { byte = (unsigned)bin; break; }
            cum += c;
        }
        vals[tt] = __uint_as_float(pfx[tt] | byte);
    }
    float q25 = vals[0] + 0.75f * (vals[1] - vals[0]);
    float q75 = vals[2] + 0.25f * (vals[3] - vals[2]);
    float iqr = q75 - q25;
    if (iqr < 1e-5f) iqr = 0.05f;
    float lo0 = q25 - 0.5f * iqr, up0 = q75 + 0.5f * iqr;

    // softmax over channel_weights (4)
    float mx = cw[0];
    for (int c = 1; c < 4; ++c) mx = cw[c] > mx ? cw[c] : mx;
    float e[4], se = 0.f;
    for (int c = 0; c < 4; ++c) { e[c] = expf(cw[c] - mx); se += e[c]; }

    float l[32], u[32], mind = 1e30f;
    for (int p = 0; p < 32; ++p) {
        float sd = stds[p];
        int c = p & 3;
        float gf = clampf(sd * 5.f, 0.5f, 2.f);
        float cf = clampf(sd * (e[c] / se) * 2.f, 0.8f, 1.2f);
        l[p] = lo0 * gf * cf;
        u[p] = up0 * gf * cf;
        float d = fabsf(u[p] - l[p]);
        if (d < mind) mind = d;
    }
    bool deg = mind < 1e-5f;
    for (int p = 0; p < 32; ++p) {
        float L = l[p], U = u[p];
        if (deg) { float m = 0.5f * (L + U); L = m - 0.05f; U = m + 0.05f; }
        lu[p] = L; lu[32 + p] = U;
    }
}

__global__ __launch_bounds__(256) void mask_k(
    const float* __restrict__ fused, const float* __restrict__ lu,
    float* __restrict__ out)
{
    const int b = blockIdx.y;
    const int i = blockIdx.x * 256 + threadIdx.x;
    float fv = fused[(size_t)b * 262144 + i];
    float s = 0.f;
#pragma unroll
    for (int c = 0; c < 4; ++c) {
        float L = lu[b * 4 + c], U = lu[32 + b * 4 + c];
        float d = U - L; d = d > 1e-5f ? d : 1e-5f;
        float n = (fv - L) / d;
        n = n < 0.f ? 0.f : (n > 1.f ? 1.f : n);
        s += 1.f / (1.f + expf(3.f - 6.f * n));
    }
    out[(size_t)b * 262144 + i] = 0.25f * s;
}

// ---------------------------------------------------------------------------
extern "C" void kernel_launch(void* const* d_in, const int* in_sizes, int n_in,
                              void* d_out, int out_size, void* d_ws, size_t ws_size,
                              hipStream_t stream)
{
    const float* x   = (const float*)d_in[0];
    const float* c1w = (const float*)d_in[1];
    const float* c1b = (const float*)d_in[2];
    const float* c2w = (const float*)d_in[3];
    const float* c2b = (const float*)d_in[4];
    const float* c3w = (const float*)d_in[5];
    const float* c3b = (const float*)d_in[6];
    const float* fw  = (const float*)d_in[7];
    const float* fb  = (const float*)d_in[8];
    const float* cwt = (const float*)d_in[9];
    float* out = (float*)d_out;
    char* ws = (char*)d_ws;

    const size_t PLANE = 512 * 512;

    // ws layout: fused | stds | lu | pfx | rem | h1|h2|h3 | partials | chunk
    float* fused = (float*)ws;
    size_t off = 8 * PLANE * sizeof(float);
    float* stds = (float*)(ws + off); off += 32 * 4;
    float* lu   = (float*)(ws + off); off += 64 * 4;
    off = (off + 255) & ~(size_t)255;
    unsigned* pfx = (unsigned*)(ws + off); off += 16;
    unsigned* rem = (unsigned*)(ws + off); off += 16;
    off = (off + 255) & ~(size_t)255;
    unsigned* h1 = (unsigned*)(ws + off); off += 4096 * 4;
    unsigned* h2 = (unsigned*)(ws + off); off += 4 * 4096 * 4;
    unsigned* h3 = (unsigned*)(ws + off); off += 4 * 256 * 4;
    off = (off + 255) & ~(size_t)255;
    double* part = (double*)(ws + off); off += 1024 * 2 * sizeof(double);
    off = (off + 1023) & ~(size_t)1023;

    // chunk buffers: f1(32ch) + f2(16ch) + f(8ch) per batch = 56 planes
    const size_t perb = 56 * PLANE * sizeof(float);
    int nb = 8;
    while (nb > 1 && off + (size_t)nb * perb > ws_size) nb >>= 1;
    float* f1  = (float*)(ws + off);
    float* f2  = f1 + (size_t)nb * 32 * PLANE;
    float* fch = f2 + (size_t)nb * 16 * PLANE;

    hipLaunchKernelGGL(plane_std_part_k, dim3(1024), dim3(256), 0, stream, x, part);
    hipLaunchKernelGGL(plane_std_fin_k,  dim3(1),    dim3(64),  0, stream, part, stds);

    for (int b0 = 0; b0 < 8; b0 += nb) {
        const float* xc = x + (size_t)b0 * 4 * PLANE;
        hipLaunchKernelGGL((conv3x3_k<4, 32, 8, true>),   dim3(8, 16, nb * 4),
                           dim3(256), 0, stream, xc, c1w, c1b, f1);
        hipLaunchKernelGGL((conv3x3_k<32, 16, 16, true>), dim3(8, 16, nb),
                           dim3(256), 0, stream, f1, c2w, c2b, f2);
        hipLaunchKernelGGL((conv3x3_k<16, 8, 8, false>),  dim3(8, 16, nb),
                           dim3(256), 0, stream, f2, c3w, c3b, fch);
        hipLaunchKernelGGL(stdmap_k, dim3(512, nb), dim3(256), 0, stream,
                           fch, fw, fb, fused, b0);
    }

    hipMemsetAsync(h1, 0, (4096 + 4 * 4096 + 4 * 256) * 4, stream);
    hipLaunchKernelGGL(hist1_k,   dim3(1024), dim3(256), 0, stream, fused, h1);
    hipLaunchKernelGGL(select1_k, dim3(1),    dim3(64),  0, stream, h1, pfx, rem);
    hipLaunchKernelGGL(hist2_k,   dim3(8192), dim3(256), 0, stream, fused, pfx, h2);
    hipLaunchKernelGGL(select2_k, dim3(1),    dim3(64),  0, stream, h2, pfx, rem);
    hipLaunchKernelGGL(hist3_k,   dim3(8192), dim3(256), 0, stream, fused, pfx, h3);
    hipLaunchKernelGGL(finalize_k, dim3(1),   dim3(64),  0, stream,
                       h3, pfx, rem, stds, cwt, lu);
    hipLaunchKernelGGL(mask_k, dim3(1024, 8), dim3(256), 0, stream, fused, lu, out);
}

// Round 3
// 1913.116 us; speedup vs baseline: 1.4294x; 1.2011x over previous
//
#include <hip/hip_runtime.h>
#include <hip/hip_bf16.h>
#include <math.h>

// ============================================================================
// RAWTextureDetector pipeline, fp32 end-to-end.
//   conv1(4->32)+lrelu -> conv2(32->16)+lrelu -> conv3(16->8)
//   3x multi-scale box-std maps (k=11,25,49, reflect pad) -> fused map
//   exact quantile (radix-histogram select) -> thresholds -> sigmoid mask
// R2: plane_std two-stage full-chip reduction (was 433us @1.3% occupancy).
// R3: hist2/hist3 LDS-merged sub-histograms (hist2 was 411us: ~2M contended
//     device-scope atomics -> 198MB fabric write traffic; now <=nonzero-bin
//     global atomics per block).
// ============================================================================

// ---------------------------------------------------------------------------
// Direct 3x3 conv, zero padding, stride 1. Tile 64x32, 256 threads.
// ---------------------------------------------------------------------------
template<int CIN, int COUT, int COT, bool LRELU>
__global__ __launch_bounds__(256) void conv3x3_k(
    const float* __restrict__ in,   // [nb, CIN, 512, 512]
    const float* __restrict__ wgt,  // [COUT, CIN, 3, 3]
    const float* __restrict__ bias, // [COUT]
    float* __restrict__ out)        // [nb, COUT, 512, 512]
{
    constexpr int TW = 64, TH = 32, CG = COUT / COT, SW = TW + 4;
    __shared__ float sl[(TH + 2) * SW];

    const int tx  = threadIdx.x & 7;    // 8 x-groups (8 px each)
    const int ty  = threadIdx.x >> 3;   // 32 rows
    const int x0  = blockIdx.x * TW;
    const int y0  = blockIdx.y * TH;
    const int cog = blockIdx.z % CG;
    const int bb  = blockIdx.z / CG;

    const float* inb = in + (size_t)bb * CIN * 512 * 512;

    float acc[COT][8];
#pragma unroll
    for (int j = 0; j < COT; ++j)
#pragma unroll
        for (int p = 0; p < 8; ++p) acc[j][p] = 0.f;

    for (int ci = 0; ci < CIN; ++ci) {
        __syncthreads();   // protect previous iteration's LDS reads
        const float* ip = inb + (size_t)ci * 512 * 512;
        for (int idx = threadIdx.x; idx < (TH + 2) * (TW + 2); idx += 256) {
            int r  = idx / (TW + 2);
            int cc = idx - r * (TW + 2);
            int yy = y0 - 1 + r, xx = x0 - 1 + cc;
            float v = 0.f;
            if ((unsigned)yy < 512u && (unsigned)xx < 512u) v = ip[yy * 512 + xx];
            sl[r * SW + cc] = v;
        }
        __syncthreads();
        const float* wci = wgt + ((size_t)(cog * COT) * CIN + ci) * 9;
#pragma unroll
        for (int dy = 0; dy < 3; ++dy) {
            const float* rowp = &sl[(ty + dy) * SW + tx * 8];  // 16B aligned
            float rr[10];
            float4 a0 = *(const float4*)(rowp);
            float4 a1 = *(const float4*)(rowp + 4);
            float2 a2 = *(const float2*)(rowp + 8);
            rr[0]=a0.x; rr[1]=a0.y; rr[2]=a0.z; rr[3]=a0.w;
            rr[4]=a1.x; rr[5]=a1.y; rr[6]=a1.z; rr[7]=a1.w;
            rr[8]=a2.x; rr[9]=a2.y;
#pragma unroll
            for (int j = 0; j < COT; ++j) {
#pragma unroll
                for (int dx = 0; dx < 3; ++dx) {
                    float w = wci[(size_t)j * CIN * 9 + dy * 3 + dx];
#pragma unroll
                    for (int p = 0; p < 8; ++p)
                        acc[j][p] = fmaf(rr[p + dx], w, acc[j][p]);
                }
            }
        }
    }

    const int y = y0 + ty;
#pragma unroll
    for (int j = 0; j < COT; ++j) {
        int co = cog * COT + j;
        float b = bias[co];
        float* op = out + (((size_t)bb * COUT + co) * 512 + y) * 512 + x0 + tx * 8;
        float v[8];
#pragma unroll
        for (int p = 0; p < 8; ++p) {
            float t = acc[j][p] + b;
            if (LRELU) t = t > 0.f ? t : 0.2f * t;
            v[p] = t;
        }
        ((float4*)op)[0] = make_float4(v[0], v[1], v[2], v[3]);
        ((float4*)op)[1] = make_float4(v[4], v[5], v[6], v[7]);
    }
}

// ---------------------------------------------------------------------------
// Multi-scale std map + fusion. One block per (row y, batch). 256 threads.
// ---------------------------------------------------------------------------
__device__ __forceinline__ float2 f2add(float2 a, float2 b) {
    return make_float2(a.x + b.x, a.y + b.y);
}

__global__ __launch_bounds__(256) void stdmap_k(
    const float* __restrict__ f,    // [nb, 8, 512, 512]
    const float* __restrict__ fw,   // fusion_w [3]
    const float* __restrict__ fbp,  // fusion_b [1]
    float* __restrict__ fused,      // [8, 512, 512] (global), offset by b0
    int b0)
{
    const int y    = blockIdx.x;
    const int bb   = blockIdx.y;
    const int t    = threadIdx.x;
    const int lane = t & 63, wid = t >> 6;

    __shared__ float Sf[513], Sq[513];
    __shared__ float2 wt[4];

    float smacc[3][2] = {{0.f,0.f},{0.f,0.f},{0.f,0.f}};

    for (int c = 0; c < 8; ++c) {
        const float* base = f + ((size_t)bb * 8 + c) * 512 * 512;
        float2 sf[3] = {{0.f,0.f},{0.f,0.f},{0.f,0.f}};  // ring sums of f
        float2 sq[3] = {{0.f,0.f},{0.f,0.f},{0.f,0.f}};  // ring sums of f^2
#pragma unroll
        for (int dy = -24; dy <= 24; ++dy) {
            int row = y + dy;
            row = row < 0 ? -row : (row > 511 ? 1022 - row : row);  // reflect
            float2 v  = ((const float2*)(base + (size_t)row * 512))[t];
            float2 vq = make_float2(v.x * v.x, v.y * v.y);
            int ad = dy < 0 ? -dy : dy;
            int ring = ad <= 5 ? 0 : (ad <= 12 ? 1 : 2);
            sf[ring] = f2add(sf[ring], v);
            sq[ring] = f2add(sq[ring], vq);
        }
        sf[1] = f2add(sf[1], sf[0]); sq[1] = f2add(sq[1], sq[0]);
        sf[2] = f2add(sf[2], sf[1]); sq[2] = f2add(sq[2], sq[1]);

        const int   RAD[3] = {5, 12, 24};
        const float INV[3] = {1.f/121.f, 1.f/625.f, 1.f/2401.f};
#pragma unroll
        for (int sc = 0; sc < 3; ++sc) {
            // block-wide inclusive scan over 512 columns of (vf, vq)
            float2 e0   = make_float2(sf[sc].x, sq[sc].x);  // x = 2t
            float2 e1   = make_float2(sf[sc].y, sq[sc].y);  // x = 2t+1
            float2 pair = f2add(e0, e1);
            float2 inc  = pair;
#pragma unroll
            for (int off = 1; off < 64; off <<= 1) {
                float2 up;
                up.x = __shfl_up(inc.x, (unsigned)off, 64);
                up.y = __shfl_up(inc.y, (unsigned)off, 64);
                if (lane >= off) inc = f2add(inc, up);
            }
            if (lane == 63) wt[wid] = inc;
            __syncthreads();
            float2 wpre = make_float2(0.f, 0.f);
#pragma unroll
            for (int w = 0; w < 4; ++w)
                if (w < wid) wpre = f2add(wpre, wt[w]);
            float exf = wpre.x + inc.x - pair.x;   // exclusive prefix (f)
            float exq = wpre.y + inc.y - pair.y;   // exclusive prefix (f^2)
            Sf[2*t+1] = exf + e0.x;           Sq[2*t+1] = exq + e0.y;
            Sf[2*t+2] = exf + e0.x + e1.x;    Sq[2*t+2] = exq + e0.y + e1.y;
            if (t == 0) { Sf[0] = 0.f; Sq[0] = 0.f; }
            __syncthreads();

            const int r = RAD[sc];
#pragma unroll
            for (int slot = 0; slot < 2; ++slot) {
                int xx = 2*t + slot;
                int lo = xx - r, hi = xx + r;
                int loc = lo < 0 ? 0 : lo;
                int hic = hi > 511 ? 511 : hi;
                float wfv = Sf[hic + 1] - Sf[loc];
                float wqv = Sq[hic + 1] - Sq[loc];
                if (lo < 0)   { wfv += Sf[r - xx + 1] - Sf[1];
                                wqv += Sq[r - xx + 1] - Sq[1]; }
                if (hi > 511) { wfv += Sf[511] - Sf[1022 - xx - r];
                                wqv += Sq[511] - Sq[1022 - xx - r]; }
                float m   = wfv * INV[sc];
                float m2  = wqv * INV[sc];
                float var = m2 - m * m;
                var = var > 1e-6f ? var : 1e-6f;
                smacc[sc][slot] += sqrtf(var);
            }
            __syncthreads();   // S buffers reused next iteration
        }
    }

    float w0 = fw[0], w1 = fw[1], w2 = fw[2], b = fbp[0];
    float o[2];
#pragma unroll
    for (int slot = 0; slot < 2; ++slot) {
        float m0 = powf(smacc[0][slot] * 0.125f, 0.8f);
        float m1 = powf(smacc[1][slot] * 0.125f, 0.8f);
        float m2 = powf(smacc[2][slot] * 0.125f, 0.8f);
        float fv = w0 * m0 + w1 * m1 + w2 * m2 + b;
        o[slot] = fv > 0.f ? fv : 0.f;
    }
    ((float2*)(fused + ((size_t)(b0 + bb) * 512 + y) * 512))[t] = make_float2(o[0], o[1]);
}

// ---------------------------------------------------------------------------
// Per-(b,c) plane std of x, ddof=1. Two-stage deterministic reduction.
// ---------------------------------------------------------------------------
__global__ __launch_bounds__(256) void plane_std_part_k(
    const float* __restrict__ x, double* __restrict__ part) // [32][32][2]
{
    const int plane = blockIdx.x >> 5;       // 0..31
    const int blk   = blockIdx.x & 31;       // 0..31
    const float* p = x + (size_t)plane * 262144 + (size_t)blk * 8192;
    double s = 0.0, s2 = 0.0;
    for (int i = threadIdx.x; i < 2048; i += 256) {
        float4 v = ((const float4*)p)[i];
        s  += (double)v.x + (double)v.y + (double)v.z + (double)v.w;
        s2 += (double)v.x * v.x + (double)v.y * v.y
            + (double)v.z * v.z + (double)v.w * v.w;
    }
    __shared__ double ls[256], ls2[256];
    ls[threadIdx.x] = s; ls2[threadIdx.x] = s2;
    __syncthreads();
    for (int off = 128; off > 0; off >>= 1) {
        if (threadIdx.x < off) {
            ls[threadIdx.x]  += ls[threadIdx.x + off];
            ls2[threadIdx.x] += ls2[threadIdx.x + off];
        }
        __syncthreads();
    }
    if (threadIdx.x == 0) {
        part[2 * blockIdx.x]     = ls[0];
        part[2 * blockIdx.x + 1] = ls2[0];
    }
}

__global__ void plane_std_fin_k(const double* __restrict__ part,
                                float* __restrict__ stds)
{
    const int plane = threadIdx.x;
    if (plane >= 32) return;
    double s = 0.0, s2 = 0.0;
    for (int b = 0; b < 32; ++b) {
        s  += part[2 * (plane * 32 + b)];
        s2 += part[2 * (plane * 32 + b) + 1];
    }
    const double N = 262144.0;
    double var = (s2 - s * s / N) / (N - 1.0);
    stds[plane] = (float)sqrt(var > 0.0 ? var : 0.0);
}

// ---------------------------------------------------------------------------
// Exact quantile via 3-level radix histogram (12+12+8 bits) on the uint
// interpretation of the (non-negative) fused values. All histogram passes
// pre-aggregate in LDS; global atomics only for nonzero bins per block.
// ---------------------------------------------------------------------------
__global__ __launch_bounds__(256) void hist1_k(
    const float* __restrict__ fused, unsigned* __restrict__ h)
{
    __shared__ unsigned lh[4096];
    for (int i = threadIdx.x; i < 4096; i += 256) lh[i] = 0u;
    __syncthreads();
    const int base = blockIdx.x * 2048;
    for (int i = threadIdx.x; i < 2048; i += 256) {
        unsigned bits = __float_as_uint(fused[base + i]);
        atomicAdd(&lh[bits >> 20], 1u);
    }
    __syncthreads();
    for (int i = threadIdx.x; i < 4096; i += 256) {
        unsigned c = lh[i];
        if (c) atomicAdd(&h[i], c);
    }
}

__global__ void select1_k(const unsigned* __restrict__ h,
                          unsigned* __restrict__ pfx, unsigned* __restrict__ rem)
{
    if (threadIdx.x < 4) {
        // order-stat ranks for q25/q75 linear interp, N = 2097152
        const unsigned targets[4] = {524287u, 524288u, 1572863u, 1572864u};
        unsigned R = targets[threadIdx.x];
        unsigned cum = 0;
        for (int bin = 0; bin < 4096; ++bin) {
            unsigned c = h[bin];
            if (cum + c > R) {
                pfx[threadIdx.x] = (unsigned)bin << 20;
                rem[threadIdx.x] = R - cum;
                return;
            }
            cum += c;
        }
        pfx[threadIdx.x] = 0xFFFu << 20; rem[threadIdx.x] = 0u;
    }
}

// grid: 1024 blocks x 2048 elems. LDS [4][4096] = 64 KB sub-histograms.
__global__ __launch_bounds__(256) void hist2_k(
    const float* __restrict__ fused, const unsigned* __restrict__ pfx,
    unsigned* __restrict__ h2)
{
    __shared__ unsigned lh[4 * 4096];
    for (int i = threadIdx.x; i < 4 * 4096; i += 256) lh[i] = 0u;
    unsigned p0 = pfx[0] >> 20, p1 = pfx[1] >> 20,
             p2 = pfx[2] >> 20, p3 = pfx[3] >> 20;
    __syncthreads();
    const int base = blockIdx.x * 2048;
    for (int i = threadIdx.x; i < 2048; i += 256) {
        unsigned bits = __float_as_uint(fused[base + i]);
        unsigned top = bits >> 20;
        unsigned mid = (bits >> 8) & 0xFFFu;
        if (top == p0) atomicAdd(&lh[0 * 4096 + mid], 1u);
        if (top == p1) atomicAdd(&lh[1 * 4096 + mid], 1u);
        if (top == p2) atomicAdd(&lh[2 * 4096 + mid], 1u);
        if (top == p3) atomicAdd(&lh[3 * 4096 + mid], 1u);
    }
    __syncthreads();
    for (int i = threadIdx.x; i < 4 * 4096; i += 256) {
        unsigned c = lh[i];
        if (c) atomicAdd(&h2[i], c);
    }
}

__global__ void select2_k(const unsigned* __restrict__ h2,
                          unsigned* __restrict__ pfx, unsigned* __restrict__ rem)
{
    if (threadIdx.x < 4) {
        unsigned R = rem[threadIdx.x];
        const unsigned* h = h2 + threadIdx.x * 4096;
        unsigned cum = 0;
        for (int bin = 0; bin < 4096; ++bin) {
            unsigned c = h[bin];
            if (cum + c > R) {
                pfx[threadIdx.x] |= (unsigned)bin << 8;
                rem[threadIdx.x] = R - cum;
                return;
            }
            cum += c;
        }
    }
}

// grid: 1024 blocks x 2048 elems. LDS [4][256] sub-histograms.
__global__ __launch_bounds__(256) void hist3_k(
    const float* __restrict__ fused, const unsigned* __restrict__ pfx,
    unsigned* __restrict__ h3)
{
    __shared__ unsigned lh[4 * 256];
    for (int i = threadIdx.x; i < 4 * 256; i += 256) lh[i] = 0u;
    unsigned p0 = pfx[0] >> 8, p1 = pfx[1] >> 8,
             p2 = pfx[2] >> 8, p3 = pfx[3] >> 8;
    __syncthreads();
    const int base = blockIdx.x * 2048;
    for (int i = threadIdx.x; i < 2048; i += 256) {
        unsigned bits = __float_as_uint(fused[base + i]);
        unsigned top = bits >> 8;
        unsigned low = bits & 0xFFu;
        if (top == p0) atomicAdd(&lh[0 * 256 + low], 1u);
        if (top == p1) atomicAdd(&lh[1 * 256 + low], 1u);
        if (top == p2) atomicAdd(&lh[2 * 256 + low], 1u);
        if (top == p3) atomicAdd(&lh[3 * 256 + low], 1u);
    }
    __syncthreads();
    for (int i = threadIdx.x; i < 4 * 256; i += 256) {
        unsigned c = lh[i];
        if (c) atomicAdd(&h3[i], c);
    }
}

__device__ __forceinline__ float clampf(float v, float lo, float hi) {
    return v < lo ? lo : (v > hi ? hi : v);
}

// select level 3 + all scalar threshold math -> lower[32], upper[32]
__global__ void finalize_k(const unsigned* __restrict__ h3,
                           const unsigned* __restrict__ pfx,
                           const unsigned* __restrict__ rem,
                           const float* __restrict__ stds,
                           const float* __restrict__ cw,
                           float* __restrict__ lu)
{
    if (threadIdx.x != 0) return;
    float vals[4];
    for (int tt = 0; tt < 4; ++tt) {
        unsigned R = rem[tt];
        const unsigned* h = h3 + tt * 256;
        unsigned cum = 0, byte = 255u;
        for (int bin = 0; bin < 256; ++bin) {
            unsigned c = h[bin];
            if (cum + c > R) { byte = (unsigned)bin; break; }
            cum += c;
        }
        vals[tt] = __uint_as_float(pfx[tt] | byte);
    }
    float q25 = vals[0] + 0.75f * (vals[1] - vals[0]);
    float q75 = vals[2] + 0.25f * (vals[3] - vals[2]);
    float iqr = q75 - q25;
    if (iqr < 1e-5f) iqr = 0.05f;
    float lo0 = q25 - 0.5f * iqr, up0 = q75 + 0.5f * iqr;

    // softmax over channel_weights (4)
    float mx = cw[0];
    for (int c = 1; c < 4; ++c) mx = cw[c] > mx ? cw[c] : mx;
    float e[4], se = 0.f;
    for (int c = 0; c < 4; ++c) { e[c] = expf(cw[c] - mx); se += e[c]; }

    float l[32], u[32], mind = 1e30f;
    for (int p = 0; p < 32; ++p) {
        float sd = stds[p];
        int c = p & 3;
        float gf = clampf(sd * 5.f, 0.5f, 2.f);
        float cf = clampf(sd * (e[c] / se) * 2.f, 0.8f, 1.2f);
        l[p] = lo0 * gf * cf;
        u[p] = up0 * gf * cf;
        float d = fabsf(u[p] - l[p]);
        if (d < mind) mind = d;
    }
    bool deg = mind < 1e-5f;
    for (int p = 0; p < 32; ++p) {
        float L = l[p], U = u[p];
        if (deg) { float m = 0.5f * (L + U); L = m - 0.05f; U = m + 0.05f; }
        lu[p] = L; lu[32 + p] = U;
    }
}

__global__ __launch_bounds__(256) void mask_k(
    const float* __restrict__ fused, const float* __restrict__ lu,
    float* __restrict__ out)
{
    const int b = blockIdx.y;
    const int i = blockIdx.x * 256 + threadIdx.x;
    float fv = fused[(size_t)b * 262144 + i];
    float s = 0.f;
#pragma unroll
    for (int c = 0; c < 4; ++c) {
        float L = lu[b * 4 + c], U = lu[32 + b * 4 + c];
        float d = U - L; d = d > 1e-5f ? d : 1e-5f;
        float n = (fv - L) / d;
        n = n < 0.f ? 0.f : (n > 1.f ? 1.f : n);
        s += 1.f / (1.f + expf(3.f - 6.f * n));
    }
    out[(size_t)b * 262144 + i] = 0.25f * s;
}

// ---------------------------------------------------------------------------
extern "C" void kernel_launch(void* const* d_in, const int* in_sizes, int n_in,
                              void* d_out, int out_size, void* d_ws, size_t ws_size,
                              hipStream_t stream)
{
    const float* x   = (const float*)d_in[0];
    const float* c1w = (const float*)d_in[1];
    const float* c1b = (const float*)d_in[2];
    const float* c2w = (const float*)d_in[3];
    const float* c2b = (const float*)d_in[4];
    const float* c3w = (const float*)d_in[5];
    const float* c3b = (const float*)d_in[6];
    const float* fw  = (const float*)d_in[7];
    const float* fb  = (const float*)d_in[8];
    const float* cwt = (const float*)d_in[9];
    float* out = (float*)d_out;
    char* ws = (char*)d_ws;

    const size_t PLANE = 512 * 512;

    // ws layout: fused | stds | lu | pfx | rem | h1|h2|h3 | partials | chunk
    float* fused = (float*)ws;
    size_t off = 8 * PLANE * sizeof(float);
    float* stds = (float*)(ws + off); off += 32 * 4;
    float* lu   = (float*)(ws + off); off += 64 * 4;
    off = (off + 255) & ~(size_t)255;
    unsigned* pfx = (unsigned*)(ws + off); off += 16;
    unsigned* rem = (unsigned*)(ws + off); off += 16;
    off = (off + 255) & ~(size_t)255;
    unsigned* h1 = (unsigned*)(ws + off); off += 4096 * 4;
    unsigned* h2 = (unsigned*)(ws + off); off += 4 * 4096 * 4;
    unsigned* h3 = (unsigned*)(ws + off); off += 4 * 256 * 4;
    off = (off + 255) & ~(size_t)255;
    double* part = (double*)(ws + off); off += 1024 * 2 * sizeof(double);
    off = (off + 1023) & ~(size_t)1023;

    // chunk buffers: f1(32ch) + f2(16ch) + f(8ch) per batch = 56 planes
    const size_t perb = 56 * PLANE * sizeof(float);
    int nb = 8;
    while (nb > 1 && off + (size_t)nb * perb > ws_size) nb >>= 1;
    float* f1  = (float*)(ws + off);
    float* f2  = f1 + (size_t)nb * 32 * PLANE;
    float* fch = f2 + (size_t)nb * 16 * PLANE;

    hipLaunchKernelGGL(plane_std_part_k, dim3(1024), dim3(256), 0, stream, x, part);
    hipLaunchKernelGGL(plane_std_fin_k,  dim3(1),    dim3(64),  0, stream, part, stds);

    for (int b0 = 0; b0 < 8; b0 += nb) {
        const float* xc = x + (size_t)b0 * 4 * PLANE;
        hipLaunchKernelGGL((conv3x3_k<4, 32, 8, true>),   dim3(8, 16, nb * 4),
                           dim3(256), 0, stream, xc, c1w, c1b, f1);
        hipLaunchKernelGGL((conv3x3_k<32, 16, 16, true>), dim3(8, 16, nb),
                           dim3(256), 0, stream, f1, c2w, c2b, f2);
        hipLaunchKernelGGL((conv3x3_k<16, 8, 8, false>),  dim3(8, 16, nb),
                           dim3(256), 0, stream, f2, c3w, c3b, fch);
        hipLaunchKernelGGL(stdmap_k, dim3(512, nb), dim3(256), 0, stream,
                           fch, fw, fb, fused, b0);
    }

    hipMemsetAsync(h1, 0, (4096 + 4 * 4096 + 4 * 256) * 4, stream);
    hipLaunchKernelGGL(hist1_k,   dim3(1024), dim3(256), 0, stream, fused, h1);
    hipLaunchKernelGGL(select1_k, dim3(1),    dim3(64),  0, stream, h1, pfx, rem);
    hipLaunchKernelGGL(hist2_k,   dim3(1024), dim3(256), 0, stream, fused, pfx, h2);
    hipLaunchKernelGGL(select2_k, dim3(1),    dim3(64),  0, stream, h2, pfx, rem);
    hipLaunchKernelGGL(hist3_k,   dim3(1024), dim3(256), 0, stream, fused, pfx, h3);
    hipLaunchKernelGGL(finalize_k, dim3(1),   dim3(64),  0, stream,
                       h3, pfx, rem, stds, cwt, lu);
    hipLaunchKernelGGL(mask_k, dim3(1024, 8), dim3(256), 0, stream, fused, lu, out);
}

// Round 4
// 1392.574 us; speedup vs baseline: 1.9637x; 1.3738x over previous
//
#include <hip/hip_runtime.h>
#include <hip/hip_bf16.h>
#include <math.h>

// ============================================================================
// RAWTextureDetector pipeline, fp32 end-to-end.
//   conv1(4->32)+lrelu -> conv2(32->16)+lrelu -> conv3(16->8)
//   3x multi-scale box-std maps (k=11,25,49, reflect pad) -> fused map
//   exact quantile (radix-histogram select) -> thresholds -> sigmoid mask
// R2: plane_std two-stage full-chip reduction (was 433us @1.3% occupancy).
// R3: hist2/hist3 LDS-merged sub-histograms (was 411us of contended atomics).
// R4: parallel histogram select (select2 was 389us: 4096 control-dependent
//     global loads = one L2 latency per bin, serialized). Block-scan select
//     in ~4us; finalize's 256-bin scan wave-parallelized too.
// ============================================================================

// ---------------------------------------------------------------------------
// Direct 3x3 conv, zero padding, stride 1. Tile 64x32, 256 threads.
// ---------------------------------------------------------------------------
template<int CIN, int COUT, int COT, bool LRELU>
__global__ __launch_bounds__(256) void conv3x3_k(
    const float* __restrict__ in,   // [nb, CIN, 512, 512]
    const float* __restrict__ wgt,  // [COUT, CIN, 3, 3]
    const float* __restrict__ bias, // [COUT]
    float* __restrict__ out)        // [nb, COUT, 512, 512]
{
    constexpr int TW = 64, TH = 32, CG = COUT / COT, SW = TW + 4;
    __shared__ float sl[(TH + 2) * SW];

    const int tx  = threadIdx.x & 7;    // 8 x-groups (8 px each)
    const int ty  = threadIdx.x >> 3;   // 32 rows
    const int x0  = blockIdx.x * TW;
    const int y0  = blockIdx.y * TH;
    const int cog = blockIdx.z % CG;
    const int bb  = blockIdx.z / CG;

    const float* inb = in + (size_t)bb * CIN * 512 * 512;

    float acc[COT][8];
#pragma unroll
    for (int j = 0; j < COT; ++j)
#pragma unroll
        for (int p = 0; p < 8; ++p) acc[j][p] = 0.f;

    for (int ci = 0; ci < CIN; ++ci) {
        __syncthreads();   // protect previous iteration's LDS reads
        const float* ip = inb + (size_t)ci * 512 * 512;
        for (int idx = threadIdx.x; idx < (TH + 2) * (TW + 2); idx += 256) {
            int r  = idx / (TW + 2);
            int cc = idx - r * (TW + 2);
            int yy = y0 - 1 + r, xx = x0 - 1 + cc;
            float v = 0.f;
            if ((unsigned)yy < 512u && (unsigned)xx < 512u) v = ip[yy * 512 + xx];
            sl[r * SW + cc] = v;
        }
        __syncthreads();
        const float* wci = wgt + ((size_t)(cog * COT) * CIN + ci) * 9;
#pragma unroll
        for (int dy = 0; dy < 3; ++dy) {
            const float* rowp = &sl[(ty + dy) * SW + tx * 8];  // 16B aligned
            float rr[10];
            float4 a0 = *(const float4*)(rowp);
            float4 a1 = *(const float4*)(rowp + 4);
            float2 a2 = *(const float2*)(rowp + 8);
            rr[0]=a0.x; rr[1]=a0.y; rr[2]=a0.z; rr[3]=a0.w;
            rr[4]=a1.x; rr[5]=a1.y; rr[6]=a1.z; rr[7]=a1.w;
            rr[8]=a2.x; rr[9]=a2.y;
#pragma unroll
            for (int j = 0; j < COT; ++j) {
#pragma unroll
                for (int dx = 0; dx < 3; ++dx) {
                    float w = wci[(size_t)j * CIN * 9 + dy * 3 + dx];
#pragma unroll
                    for (int p = 0; p < 8; ++p)
                        acc[j][p] = fmaf(rr[p + dx], w, acc[j][p]);
                }
            }
        }
    }

    const int y = y0 + ty;
#pragma unroll
    for (int j = 0; j < COT; ++j) {
        int co = cog * COT + j;
        float b = bias[co];
        float* op = out + (((size_t)bb * COUT + co) * 512 + y) * 512 + x0 + tx * 8;
        float v[8];
#pragma unroll
        for (int p = 0; p < 8; ++p) {
            float t = acc[j][p] + b;
            if (LRELU) t = t > 0.f ? t : 0.2f * t;
            v[p] = t;
        }
        ((float4*)op)[0] = make_float4(v[0], v[1], v[2], v[3]);
        ((float4*)op)[1] = make_float4(v[4], v[5], v[6], v[7]);
    }
}

// ---------------------------------------------------------------------------
// Multi-scale std map + fusion. One block per (row y, batch). 256 threads.
// ---------------------------------------------------------------------------
__device__ __forceinline__ float2 f2add(float2 a, float2 b) {
    return make_float2(a.x + b.x, a.y + b.y);
}

__global__ __launch_bounds__(256) void stdmap_k(
    const float* __restrict__ f,    // [nb, 8, 512, 512]
    const float* __restrict__ fw,   // fusion_w [3]
    const float* __restrict__ fbp,  // fusion_b [1]
    float* __restrict__ fused,      // [8, 512, 512] (global), offset by b0
    int b0)
{
    const int y    = blockIdx.x;
    const int bb   = blockIdx.y;
    const int t    = threadIdx.x;
    const int lane = t & 63, wid = t >> 6;

    __shared__ float Sf[513], Sq[513];
    __shared__ float2 wt[4];

    float smacc[3][2] = {{0.f,0.f},{0.f,0.f},{0.f,0.f}};

    for (int c = 0; c < 8; ++c) {
        const float* base = f + ((size_t)bb * 8 + c) * 512 * 512;
        float2 sf[3] = {{0.f,0.f},{0.f,0.f},{0.f,0.f}};  // ring sums of f
        float2 sq[3] = {{0.f,0.f},{0.f,0.f},{0.f,0.f}};  // ring sums of f^2
#pragma unroll
        for (int dy = -24; dy <= 24; ++dy) {
            int row = y + dy;
            row = row < 0 ? -row : (row > 511 ? 1022 - row : row);  // reflect
            float2 v  = ((const float2*)(base + (size_t)row * 512))[t];
            float2 vq = make_float2(v.x * v.x, v.y * v.y);
            int ad = dy < 0 ? -dy : dy;
            int ring = ad <= 5 ? 0 : (ad <= 12 ? 1 : 2);
            sf[ring] = f2add(sf[ring], v);
            sq[ring] = f2add(sq[ring], vq);
        }
        sf[1] = f2add(sf[1], sf[0]); sq[1] = f2add(sq[1], sq[0]);
        sf[2] = f2add(sf[2], sf[1]); sq[2] = f2add(sq[2], sq[1]);

        const int   RAD[3] = {5, 12, 24};
        const float INV[3] = {1.f/121.f, 1.f/625.f, 1.f/2401.f};
#pragma unroll
        for (int sc = 0; sc < 3; ++sc) {
            // block-wide inclusive scan over 512 columns of (vf, vq)
            float2 e0   = make_float2(sf[sc].x, sq[sc].x);  // x = 2t
            float2 e1   = make_float2(sf[sc].y, sq[sc].y);  // x = 2t+1
            float2 pair = f2add(e0, e1);
            float2 inc  = pair;
#pragma unroll
            for (int off = 1; off < 64; off <<= 1) {
                float2 up;
                up.x = __shfl_up(inc.x, (unsigned)off, 64);
                up.y = __shfl_up(inc.y, (unsigned)off, 64);
                if (lane >= off) inc = f2add(inc, up);
            }
            if (lane == 63) wt[wid] = inc;
            __syncthreads();
            float2 wpre = make_float2(0.f, 0.f);
#pragma unroll
            for (int w = 0; w < 4; ++w)
                if (w < wid) wpre = f2add(wpre, wt[w]);
            float exf = wpre.x + inc.x - pair.x;   // exclusive prefix (f)
            float exq = wpre.y + inc.y - pair.y;   // exclusive prefix (f^2)
            Sf[2*t+1] = exf + e0.x;           Sq[2*t+1] = exq + e0.y;
            Sf[2*t+2] = exf + e0.x + e1.x;    Sq[2*t+2] = exq + e0.y + e1.y;
            if (t == 0) { Sf[0] = 0.f; Sq[0] = 0.f; }
            __syncthreads();

            const int r = RAD[sc];
#pragma unroll
            for (int slot = 0; slot < 2; ++slot) {
                int xx = 2*t + slot;
                int lo = xx - r, hi = xx + r;
                int loc = lo < 0 ? 0 : lo;
                int hic = hi > 511 ? 511 : hi;
                float wfv = Sf[hic + 1] - Sf[loc];
                float wqv = Sq[hic + 1] - Sq[loc];
                if (lo < 0)   { wfv += Sf[r - xx + 1] - Sf[1];
                                wqv += Sq[r - xx + 1] - Sq[1]; }
                if (hi > 511) { wfv += Sf[511] - Sf[1022 - xx - r];
                                wqv += Sq[511] - Sq[1022 - xx - r]; }
                float m   = wfv * INV[sc];
                float m2  = wqv * INV[sc];
                float var = m2 - m * m;
                var = var > 1e-6f ? var : 1e-6f;
                smacc[sc][slot] += sqrtf(var);
            }
            __syncthreads();   // S buffers reused next iteration
        }
    }

    float w0 = fw[0], w1 = fw[1], w2 = fw[2], b = fbp[0];
    float o[2];
#pragma unroll
    for (int slot = 0; slot < 2; ++slot) {
        float m0 = powf(smacc[0][slot] * 0.125f, 0.8f);
        float m1 = powf(smacc[1][slot] * 0.125f, 0.8f);
        float m2 = powf(smacc[2][slot] * 0.125f, 0.8f);
        float fv = w0 * m0 + w1 * m1 + w2 * m2 + b;
        o[slot] = fv > 0.f ? fv : 0.f;
    }
    ((float2*)(fused + ((size_t)(b0 + bb) * 512 + y) * 512))[t] = make_float2(o[0], o[1]);
}

// ---------------------------------------------------------------------------
// Per-(b,c) plane std of x, ddof=1. Two-stage deterministic reduction.
// ---------------------------------------------------------------------------
__global__ __launch_bounds__(256) void plane_std_part_k(
    const float* __restrict__ x, double* __restrict__ part) // [32][32][2]
{
    const int plane = blockIdx.x >> 5;       // 0..31
    const int blk   = blockIdx.x & 31;       // 0..31
    const float* p = x + (size_t)plane * 262144 + (size_t)blk * 8192;
    double s = 0.0, s2 = 0.0;
    for (int i = threadIdx.x; i < 2048; i += 256) {
        float4 v = ((const float4*)p)[i];
        s  += (double)v.x + (double)v.y + (double)v.z + (double)v.w;
        s2 += (double)v.x * v.x + (double)v.y * v.y
            + (double)v.z * v.z + (double)v.w * v.w;
    }
    __shared__ double ls[256], ls2[256];
    ls[threadIdx.x] = s; ls2[threadIdx.x] = s2;
    __syncthreads();
    for (int off = 128; off > 0; off >>= 1) {
        if (threadIdx.x < off) {
            ls[threadIdx.x]  += ls[threadIdx.x + off];
            ls2[threadIdx.x] += ls2[threadIdx.x + off];
        }
        __syncthreads();
    }
    if (threadIdx.x == 0) {
        part[2 * blockIdx.x]     = ls[0];
        part[2 * blockIdx.x + 1] = ls2[0];
    }
}

__global__ void plane_std_fin_k(const double* __restrict__ part,
                                float* __restrict__ stds)
{
    const int plane = threadIdx.x;
    if (plane >= 32) return;
    double s = 0.0, s2 = 0.0;
    for (int b = 0; b < 32; ++b) {
        s  += part[2 * (plane * 32 + b)];
        s2 += part[2 * (plane * 32 + b) + 1];
    }
    const double N = 262144.0;
    double var = (s2 - s * s / N) / (N - 1.0);
    stds[plane] = (float)sqrt(var > 0.0 ? var : 0.0);
}

// ---------------------------------------------------------------------------
// Exact quantile via 3-level radix histogram (12+12+8 bits) on the uint
// interpretation of the (non-negative) fused values. LDS sub-histograms;
// block-parallel rank select.
// ---------------------------------------------------------------------------
__global__ __launch_bounds__(256) void hist1_k(
    const float* __restrict__ fused, unsigned* __restrict__ h)
{
    __shared__ unsigned lh[4096];
    for (int i = threadIdx.x; i < 4096; i += 256) lh[i] = 0u;
    __syncthreads();
    const int base = blockIdx.x * 2048;
    for (int i = threadIdx.x; i < 2048; i += 256) {
        unsigned bits = __float_as_uint(fused[base + i]);
        atomicAdd(&lh[bits >> 20], 1u);
    }
    __syncthreads();
    for (int i = threadIdx.x; i < 4096; i += 256) {
        unsigned c = lh[i];
        if (c) atomicAdd(&h[i], c);
    }
}

// Parallel rank-select over a 4096-bin histogram. grid = 4 (one block per
// target). level 1: shared h1, rank = quantile targets, pfx = bin<<20.
// level 2: per-target h2 slice, rank = rem[tt], pfx |= bin<<8.
__global__ __launch_bounds__(256) void select_par_k(
    const unsigned* __restrict__ h, unsigned* __restrict__ pfx,
    unsigned* __restrict__ rem, int level)
{
    const int tt = blockIdx.x;
    const int t = threadIdx.x, lane = t & 63, wid = t >> 6;
    const unsigned targets[4] = {524287u, 524288u, 1572863u, 1572864u};
    const unsigned R = (level == 1) ? targets[tt] : rem[tt];
    const unsigned* hb = (level == 1) ? h : h + tt * 4096;

    unsigned loc[16], lsum = 0;
    const uint4* hv = (const uint4*)(hb + t * 16);
#pragma unroll
    for (int i = 0; i < 4; ++i) {
        uint4 v = hv[i];
        loc[4*i]=v.x; loc[4*i+1]=v.y; loc[4*i+2]=v.z; loc[4*i+3]=v.w;
        lsum += v.x + v.y + v.z + v.w;
    }
    // block exclusive scan of per-thread sums
    __shared__ unsigned warr[4];
    __shared__ unsigned rbin, rrem;
    unsigned inc = lsum;
#pragma unroll
    for (int off = 1; off < 64; off <<= 1) {
        unsigned up = __shfl_up(inc, (unsigned)off, 64);
        if (lane >= off) inc += up;
    }
    if (lane == 63) warr[wid] = inc;
    __syncthreads();
    unsigned wpre = 0;
#pragma unroll
    for (int w = 0; w < 4; ++w) if (w < wid) wpre += warr[w];
    unsigned ex = wpre + inc - lsum;
    // exactly one thread's disjoint interval [ex, ex+lsum) contains R
    if (R >= ex && R < ex + lsum) {
        unsigned cum = ex;
#pragma unroll
        for (int i = 0; i < 16; ++i) {
            if (cum + loc[i] > R) { rbin = (unsigned)(t * 16 + i); rrem = R - cum; break; }
            cum += loc[i];
        }
    }
    __syncthreads();
    if (t == 0) {
        if (level == 1) { pfx[tt] = rbin << 20; rem[tt] = rrem; }
        else            { pfx[tt] |= rbin << 8; rem[tt] = rrem; }
    }
}

// grid: 1024 blocks x 2048 elems. LDS [4][4096] = 64 KB sub-histograms.
__global__ __launch_bounds__(256) void hist2_k(
    const float* __restrict__ fused, const unsigned* __restrict__ pfx,
    unsigned* __restrict__ h2)
{
    __shared__ unsigned lh[4 * 4096];
    for (int i = threadIdx.x; i < 4 * 4096; i += 256) lh[i] = 0u;
    unsigned p0 = pfx[0] >> 20, p1 = pfx[1] >> 20,
             p2 = pfx[2] >> 20, p3 = pfx[3] >> 20;
    __syncthreads();
    const int base = blockIdx.x * 2048;
    for (int i = threadIdx.x; i < 2048; i += 256) {
        unsigned bits = __float_as_uint(fused[base + i]);
        unsigned top = bits >> 20;
        unsigned mid = (bits >> 8) & 0xFFFu;
        if (top == p0) atomicAdd(&lh[0 * 4096 + mid], 1u);
        if (top == p1) atomicAdd(&lh[1 * 4096 + mid], 1u);
        if (top == p2) atomicAdd(&lh[2 * 4096 + mid], 1u);
        if (top == p3) atomicAdd(&lh[3 * 4096 + mid], 1u);
    }
    __syncthreads();
    for (int i = threadIdx.x; i < 4 * 4096; i += 256) {
        unsigned c = lh[i];
        if (c) atomicAdd(&h2[i], c);
    }
}

// grid: 1024 blocks x 2048 elems. LDS [4][256] sub-histograms.
__global__ __launch_bounds__(256) void hist3_k(
    const float* __restrict__ fused, const unsigned* __restrict__ pfx,
    unsigned* __restrict__ h3)
{
    __shared__ unsigned lh[4 * 256];
    for (int i = threadIdx.x; i < 4 * 256; i += 256) lh[i] = 0u;
    unsigned p0 = pfx[0] >> 8, p1 = pfx[1] >> 8,
             p2 = pfx[2] >> 8, p3 = pfx[3] >> 8;
    __syncthreads();
    const int base = blockIdx.x * 2048;
    for (int i = threadIdx.x; i < 2048; i += 256) {
        unsigned bits = __float_as_uint(fused[base + i]);
        unsigned top = bits >> 8;
        unsigned low = bits & 0xFFu;
        if (top == p0) atomicAdd(&lh[0 * 256 + low], 1u);
        if (top == p1) atomicAdd(&lh[1 * 256 + low], 1u);
        if (top == p2) atomicAdd(&lh[2 * 256 + low], 1u);
        if (top == p3) atomicAdd(&lh[3 * 256 + low], 1u);
    }
    __syncthreads();
    for (int i = threadIdx.x; i < 4 * 256; i += 256) {
        unsigned c = lh[i];
        if (c) atomicAdd(&h3[i], c);
    }
}

__device__ __forceinline__ float clampf(float v, float lo, float hi) {
    return v < lo ? lo : (v > hi ? hi : v);
}

// Level-3 select (wave-parallel: 4 waves x 64 lanes x 4 bins) + scalar
// threshold math on thread 0.
__global__ __launch_bounds__(256) void finalize_k(
    const unsigned* __restrict__ h3,
    const unsigned* __restrict__ pfx,
    const unsigned* __restrict__ rem,
    const float* __restrict__ stds,
    const float* __restrict__ cw,
    float* __restrict__ lu)
{
    const int tt = threadIdx.x >> 6, lane = threadIdx.x & 63;
    __shared__ float vals[4];

    {
        const unsigned R = rem[tt];
        const unsigned* h = h3 + tt * 256;
        uint4 v = ((const uint4*)h)[lane];
        unsigned loc[4] = {v.x, v.y, v.z, v.w};
        unsigned lsum = v.x + v.y + v.z + v.w;
        unsigned inc = lsum;
#pragma unroll
        for (int off = 1; off < 64; off <<= 1) {
            unsigned up = __shfl_up(inc, (unsigned)off, 64);
            if (lane >= off) inc += up;
        }
        unsigned ex = inc - lsum;
        if (R >= ex && R < ex + lsum) {
            unsigned cum = ex;
#pragma unroll
            for (int i = 0; i < 4; ++i) {
                if (cum + loc[i] > R) {
                    vals[tt] = __uint_as_float(pfx[tt] | (unsigned)(lane * 4 + i));
                    break;
                }
                cum += loc[i];
            }
        }
    }
    __syncthreads();
    if (threadIdx.x != 0) return;

    float q25 = vals[0] + 0.75f * (vals[1] - vals[0]);
    float q75 = vals[2] + 0.25f * (vals[3] - vals[2]);
    float iqr = q75 - q25;
    if (iqr < 1e-5f) iqr = 0.05f;
    float lo0 = q25 - 0.5f * iqr, up0 = q75 + 0.5f * iqr;

    // softmax over channel_weights (4)
    float mx = cw[0];
    for (int c = 1; c < 4; ++c) mx = cw[c] > mx ? cw[c] : mx;
    float e[4], se = 0.f;
    for (int c = 0; c < 4; ++c) { e[c] = expf(cw[c] - mx); se += e[c]; }

    float l[32], u[32], mind = 1e30f;
    for (int p = 0; p < 32; ++p) {
        float sd = stds[p];
        int c = p & 3;
        float gf = clampf(sd * 5.f, 0.5f, 2.f);
        float cf = clampf(sd * (e[c] / se) * 2.f, 0.8f, 1.2f);
        l[p] = lo0 * gf * cf;
        u[p] = up0 * gf * cf;
        float d = fabsf(u[p] - l[p]);
        if (d < mind) mind = d;
    }
    bool deg = mind < 1e-5f;
    for (int p = 0; p < 32; ++p) {
        float L = l[p], U = u[p];
        if (deg) { float m = 0.5f * (L + U); L = m - 0.05f; U = m + 0.05f; }
        lu[p] = L; lu[32 + p] = U;
    }
}

__global__ __launch_bounds__(256) void mask_k(
    const float* __restrict__ fused, const float* __restrict__ lu,
    float* __restrict__ out)
{
    const int b = blockIdx.y;
    const int i = blockIdx.x * 256 + threadIdx.x;
    float fv = fused[(size_t)b * 262144 + i];
    float s = 0.f;
#pragma unroll
    for (int c = 0; c < 4; ++c) {
        float L = lu[b * 4 + c], U = lu[32 + b * 4 + c];
        float d = U - L; d = d > 1e-5f ? d : 1e-5f;
        float n = (fv - L) / d;
        n = n < 0.f ? 0.f : (n > 1.f ? 1.f : n);
        s += 1.f / (1.f + expf(3.f - 6.f * n));
    }
    out[(size_t)b * 262144 + i] = 0.25f * s;
}

// ---------------------------------------------------------------------------
extern "C" void kernel_launch(void* const* d_in, const int* in_sizes, int n_in,
                              void* d_out, int out_size, void* d_ws, size_t ws_size,
                              hipStream_t stream)
{
    const float* x   = (const float*)d_in[0];
    const float* c1w = (const float*)d_in[1];
    const float* c1b = (const float*)d_in[2];
    const float* c2w = (const float*)d_in[3];
    const float* c2b = (const float*)d_in[4];
    const float* c3w = (const float*)d_in[5];
    const float* c3b = (const float*)d_in[6];
    const float* fw  = (const float*)d_in[7];
    const float* fb  = (const float*)d_in[8];
    const float* cwt = (const float*)d_in[9];
    float* out = (float*)d_out;
    char* ws = (char*)d_ws;

    const size_t PLANE = 512 * 512;

    // ws layout: fused | stds | lu | pfx | rem | h1|h2|h3 | partials | chunk
    float* fused = (float*)ws;
    size_t off = 8 * PLANE * sizeof(float);
    float* stds = (float*)(ws + off); off += 32 * 4;
    float* lu   = (float*)(ws + off); off += 64 * 4;
    off = (off + 255) & ~(size_t)255;
    unsigned* pfx = (unsigned*)(ws + off); off += 16;
    unsigned* rem = (unsigned*)(ws + off); off += 16;
    off = (off + 255) & ~(size_t)255;
    unsigned* h1 = (unsigned*)(ws + off); off += 4096 * 4;
    unsigned* h2 = (unsigned*)(ws + off); off += 4 * 4096 * 4;
    unsigned* h3 = (unsigned*)(ws + off); off += 4 * 256 * 4;
    off = (off + 255) & ~(size_t)255;
    double* part = (double*)(ws + off); off += 1024 * 2 * sizeof(double);
    off = (off + 1023) & ~(size_t)1023;

    // chunk buffers: f1(32ch) + f2(16ch) + f(8ch) per batch = 56 planes
    const size_t perb = 56 * PLANE * sizeof(float);
    int nb = 8;
    while (nb > 1 && off + (size_t)nb * perb > ws_size) nb >>= 1;
    float* f1  = (float*)(ws + off);
    float* f2  = f1 + (size_t)nb * 32 * PLANE;
    float* fch = f2 + (size_t)nb * 16 * PLANE;

    hipLaunchKernelGGL(plane_std_part_k, dim3(1024), dim3(256), 0, stream, x, part);
    hipLaunchKernelGGL(plane_std_fin_k,  dim3(1),    dim3(64),  0, stream, part, stds);

    for (int b0 = 0; b0 < 8; b0 += nb) {
        const float* xc = x + (size_t)b0 * 4 * PLANE;
        hipLaunchKernelGGL((conv3x3_k<4, 32, 8, true>),   dim3(8, 16, nb * 4),
                           dim3(256), 0, stream, xc, c1w, c1b, f1);
        hipLaunchKernelGGL((conv3x3_k<32, 16, 16, true>), dim3(8, 16, nb),
                           dim3(256), 0, stream, f1, c2w, c2b, f2);
        hipLaunchKernelGGL((conv3x3_k<16, 8, 8, false>),  dim3(8, 16, nb),
                           dim3(256), 0, stream, f2, c3w, c3b, fch);
        hipLaunchKernelGGL(stdmap_k, dim3(512, nb), dim3(256), 0, stream,
                           fch, fw, fb, fused, b0);
    }

    hipMemsetAsync(h1, 0, (4096 + 4 * 4096 + 4 * 256) * 4, stream);
    hipLaunchKernelGGL(hist1_k,     dim3(1024), dim3(256), 0, stream, fused, h1);
    hipLaunchKernelGGL(select_par_k, dim3(4),   dim3(256), 0, stream, h1, pfx, rem, 1);
    hipLaunchKernelGGL(hist2_k,     dim3(1024), dim3(256), 0, stream, fused, pfx, h2);
    hipLaunchKernelGGL(select_par_k, dim3(4),   dim3(256), 0, stream, h2, pfx, rem, 2);
    hipLaunchKernelGGL(hist3_k,     dim3(1024), dim3(256), 0, stream, fused, pfx, h3);
    hipLaunchKernelGGL(finalize_k,  dim3(1),    dim3(256), 0, stream,
                       h3, pfx, rem, stds, cwt, lu);
    hipLaunchKernelGGL(mask_k, dim3(1024, 8), dim3(256), 0, stream, fused, lu, out);
}

// Round 5
// 1232.762 us; speedup vs baseline: 2.2183x; 1.1296x over previous
//
#include <hip/hip_runtime.h>
#include <hip/hip_bf16.h>
#include <math.h>

// ============================================================================
// RAWTextureDetector pipeline, fp32 end-to-end.
//   conv1(4->32)+lrelu -> conv2(32->16)+lrelu -> conv3(16->8)
//   3x multi-scale box-std maps (k=11,25,49, reflect pad) -> fused map
//   exact quantile (radix-histogram select) -> thresholds -> sigmoid mask
// R2: plane_std two-stage full-chip reduction (was 433us @1.3% occupancy).
// R3: hist2/hist3 LDS-merged sub-histograms (was 411us of contended atomics).
// R4: parallel histogram select (was 389us of serial L2-latency bin scans).
// R5: stdmap YB=4 multi-row blocks w/ sliding vertical windows (49->16.75
//     row-loads per output row; was 3.2GB L2 traffic) + merged 3-scale scan
//     (one barrier set per (ch,row) instead of three; 6 ILP shfl chains).
// ============================================================================

// ---------------------------------------------------------------------------
// Direct 3x3 conv, zero padding, stride 1. Tile 64x32, 256 threads.
// ---------------------------------------------------------------------------
template<int CIN, int COUT, int COT, bool LRELU>
__global__ __launch_bounds__(256) void conv3x3_k(
    const float* __restrict__ in,   // [nb, CIN, 512, 512]
    const float* __restrict__ wgt,  // [COUT, CIN, 3, 3]
    const float* __restrict__ bias, // [COUT]
    float* __restrict__ out)        // [nb, COUT, 512, 512]
{
    constexpr int TW = 64, TH = 32, CG = COUT / COT, SW = TW + 4;
    __shared__ float sl[(TH + 2) * SW];

    const int tx  = threadIdx.x & 7;    // 8 x-groups (8 px each)
    const int ty  = threadIdx.x >> 3;   // 32 rows
    const int x0  = blockIdx.x * TW;
    const int y0  = blockIdx.y * TH;
    const int cog = blockIdx.z % CG;
    const int bb  = blockIdx.z / CG;

    const float* inb = in + (size_t)bb * CIN * 512 * 512;

    float acc[COT][8];
#pragma unroll
    for (int j = 0; j < COT; ++j)
#pragma unroll
        for (int p = 0; p < 8; ++p) acc[j][p] = 0.f;

    for (int ci = 0; ci < CIN; ++ci) {
        __syncthreads();   // protect previous iteration's LDS reads
        const float* ip = inb + (size_t)ci * 512 * 512;
        for (int idx = threadIdx.x; idx < (TH + 2) * (TW + 2); idx += 256) {
            int r  = idx / (TW + 2);
            int cc = idx - r * (TW + 2);
            int yy = y0 - 1 + r, xx = x0 - 1 + cc;
            float v = 0.f;
            if ((unsigned)yy < 512u && (unsigned)xx < 512u) v = ip[yy * 512 + xx];
            sl[r * SW + cc] = v;
        }
        __syncthreads();
        const float* wci = wgt + ((size_t)(cog * COT) * CIN + ci) * 9;
#pragma unroll
        for (int dy = 0; dy < 3; ++dy) {
            const float* rowp = &sl[(ty + dy) * SW + tx * 8];  // 16B aligned
            float rr[10];
            float4 a0 = *(const float4*)(rowp);
            float4 a1 = *(const float4*)(rowp + 4);
            float2 a2 = *(const float2*)(rowp + 8);
            rr[0]=a0.x; rr[1]=a0.y; rr[2]=a0.z; rr[3]=a0.w;
            rr[4]=a1.x; rr[5]=a1.y; rr[6]=a1.z; rr[7]=a1.w;
            rr[8]=a2.x; rr[9]=a2.y;
#pragma unroll
            for (int j = 0; j < COT; ++j) {
#pragma unroll
                for (int dx = 0; dx < 3; ++dx) {
                    float w = wci[(size_t)j * CIN * 9 + dy * 3 + dx];
#pragma unroll
                    for (int p = 0; p < 8; ++p)
                        acc[j][p] = fmaf(rr[p + dx], w, acc[j][p]);
                }
            }
        }
    }

    const int y = y0 + ty;
#pragma unroll
    for (int j = 0; j < COT; ++j) {
        int co = cog * COT + j;
        float b = bias[co];
        float* op = out + (((size_t)bb * COUT + co) * 512 + y) * 512 + x0 + tx * 8;
        float v[8];
#pragma unroll
        for (int p = 0; p < 8; ++p) {
            float t = acc[j][p] + b;
            if (LRELU) t = t > 0.f ? t : 0.2f * t;
            v[p] = t;
        }
        ((float4*)op)[0] = make_float4(v[0], v[1], v[2], v[3]);
        ((float4*)op)[1] = make_float4(v[4], v[5], v[6], v[7]);
    }
}

// ---------------------------------------------------------------------------
// Multi-scale std map + fusion. Block = (YB output rows, batch). 256 threads,
// each owns columns x = 2t, 2t+1. Vertical window sums built once via nested
// rings, then slid row-to-row (add/sub mirrored boundary rows). Horizontal:
// one merged scan per (channel,row) covering all 3 scales (6 shfl chains).
// ---------------------------------------------------------------------------
__device__ __forceinline__ float2 f2add(float2 a, float2 b) {
    return make_float2(a.x + b.x, a.y + b.y);
}
__device__ __forceinline__ int mir(int v) {
    return v < 0 ? -v : (v > 511 ? 1022 - v : v);
}

#define YB 4

__global__ __launch_bounds__(256) void stdmap_k(
    const float* __restrict__ f,    // [nb, 8, 512, 512]
    const float* __restrict__ fw,   // fusion_w [3]
    const float* __restrict__ fbp,  // fusion_b [1]
    float* __restrict__ fused,      // [8, 512, 512] (global), offset by b0
    int b0)
{
    const int y0   = blockIdx.x * YB;
    const int bb   = blockIdx.y;
    const int t    = threadIdx.x;
    const int lane = t & 63, wid = t >> 6;

    __shared__ float S[3][2][513];   // per-scale prefix arrays (f, f^2)
    __shared__ float wtt[4][6];      // per-wave scan totals, 6 chains

    const int   RAD[3] = {5, 12, 24};
    const float INV[3] = {1.f/121.f, 1.f/625.f, 1.f/2401.f};

    float smacc[3][YB][2];
#pragma unroll
    for (int sc = 0; sc < 3; ++sc)
#pragma unroll
        for (int yy = 0; yy < YB; ++yy)
            { smacc[sc][yy][0] = 0.f; smacc[sc][yy][1] = 0.f; }

    for (int c = 0; c < 8; ++c) {
        const float* base = f + ((size_t)bb * 8 + c) * 512 * 512;

        // ---- initial vertical window sums for y0 (nested rings) ----
        float2 wf[3], wq[3];
        {
            float2 sf[3] = {{0.f,0.f},{0.f,0.f},{0.f,0.f}};
            float2 sq[3] = {{0.f,0.f},{0.f,0.f},{0.f,0.f}};
#pragma unroll
            for (int dy = -24; dy <= 24; ++dy) {
                int row = mir(y0 + dy);
                float2 v  = ((const float2*)(base + (size_t)row * 512))[t];
                float2 vq = make_float2(v.x * v.x, v.y * v.y);
                int ad = dy < 0 ? -dy : dy;
                int ring = ad <= 5 ? 0 : (ad <= 12 ? 1 : 2);
                sf[ring] = f2add(sf[ring], v);
                sq[ring] = f2add(sq[ring], vq);
            }
            wf[0] = sf[0];              wq[0] = sq[0];
            wf[1] = f2add(sf[1], wf[0]); wq[1] = f2add(sq[1], wq[0]);
            wf[2] = f2add(sf[2], wf[1]); wq[2] = f2add(sq[2], wq[1]);
        }

        for (int yy = 0; yy < YB; ++yy) {
            const int y = y0 + yy;
            if (yy > 0) {
                // slide each window: add row mir(y+r), subtract mir(y-1-r)
#pragma unroll
                for (int sc = 0; sc < 3; ++sc) {
                    int ra = mir(y + RAD[sc]);
                    int rs = mir(y - 1 - RAD[sc]);
                    float2 va = ((const float2*)(base + (size_t)ra * 512))[t];
                    float2 vs = ((const float2*)(base + (size_t)rs * 512))[t];
                    wf[sc].x += va.x - vs.x;       wf[sc].y += va.y - vs.y;
                    wq[sc].x += va.x*va.x - vs.x*vs.x;
                    wq[sc].y += va.y*va.y - vs.y*vs.y;
                }
            }

            // ---- merged 3-scale block scan (6 independent chains) ----
            float pf[3], pq[3], incf[3], incq[3];
#pragma unroll
            for (int sc = 0; sc < 3; ++sc) {
                pf[sc] = wf[sc].x + wf[sc].y;
                pq[sc] = wq[sc].x + wq[sc].y;
                incf[sc] = pf[sc]; incq[sc] = pq[sc];
            }
#pragma unroll
            for (int off = 1; off < 64; off <<= 1) {
#pragma unroll
                for (int sc = 0; sc < 3; ++sc) {
                    float uf = __shfl_up(incf[sc], (unsigned)off, 64);
                    float uq = __shfl_up(incq[sc], (unsigned)off, 64);
                    if (lane >= off) { incf[sc] += uf; incq[sc] += uq; }
                }
            }
            if (lane == 63) {
#pragma unroll
                for (int sc = 0; sc < 3; ++sc) {
                    wtt[wid][sc]     = incf[sc];
                    wtt[wid][3 + sc] = incq[sc];
                }
            }
            __syncthreads();
            float wpf[3] = {0.f,0.f,0.f}, wpq[3] = {0.f,0.f,0.f};
#pragma unroll
            for (int w = 0; w < 4; ++w)
                if (w < wid)
#pragma unroll
                    for (int sc = 0; sc < 3; ++sc) {
                        wpf[sc] += wtt[w][sc];
                        wpq[sc] += wtt[w][3 + sc];
                    }
#pragma unroll
            for (int sc = 0; sc < 3; ++sc) {
                float exf = wpf[sc] + incf[sc] - pf[sc];   // exclusive prefix
                float exq = wpq[sc] + incq[sc] - pq[sc];
                S[sc][0][2*t+1] = exf + wf[sc].x;
                S[sc][0][2*t+2] = exf + pf[sc];
                S[sc][1][2*t+1] = exq + wq[sc].x;
                S[sc][1][2*t+2] = exq + pq[sc];
            }
            if (t == 0)
#pragma unroll
                for (int sc = 0; sc < 3; ++sc)
                    { S[sc][0][0] = 0.f; S[sc][1][0] = 0.f; }
            __syncthreads();

            // ---- horizontal window extraction, all 3 scales ----
#pragma unroll
            for (int sc = 0; sc < 3; ++sc) {
                const int r = RAD[sc];
                const float* Sf = S[sc][0];
                const float* Sq = S[sc][1];
#pragma unroll
                for (int slot = 0; slot < 2; ++slot) {
                    int xx = 2*t + slot;
                    int lo = xx - r, hi = xx + r;
                    int loc = lo < 0 ? 0 : lo;
                    int hic = hi > 511 ? 511 : hi;
                    float wfv = Sf[hic + 1] - Sf[loc];
                    float wqv = Sq[hic + 1] - Sq[loc];
                    if (lo < 0)   { wfv += Sf[r - xx + 1] - Sf[1];
                                    wqv += Sq[r - xx + 1] - Sq[1]; }
                    if (hi > 511) { wfv += Sf[511] - Sf[1022 - xx - r];
                                    wqv += Sq[511] - Sq[1022 - xx - r]; }
                    float m   = wfv * INV[sc];
                    float m2  = wqv * INV[sc];
                    float var = m2 - m * m;
                    var = var > 1e-6f ? var : 1e-6f;
                    smacc[sc][yy][slot] += sqrtf(var);
                }
            }
            __syncthreads();   // S/wtt reused next row / next channel
        }
    }

    const float w0 = fw[0], w1 = fw[1], w2 = fw[2], b = fbp[0];
#pragma unroll
    for (int yy = 0; yy < YB; ++yy) {
        float o[2];
#pragma unroll
        for (int slot = 0; slot < 2; ++slot) {
            float m0 = powf(smacc[0][yy][slot] * 0.125f, 0.8f);
            float m1 = powf(smacc[1][yy][slot] * 0.125f, 0.8f);
            float m2 = powf(smacc[2][yy][slot] * 0.125f, 0.8f);
            float fv = w0 * m0 + w1 * m1 + w2 * m2 + b;
            o[slot] = fv > 0.f ? fv : 0.f;
        }
        ((float2*)(fused + ((size_t)(b0 + bb) * 512 + y0 + yy) * 512))[t] =
            make_float2(o[0], o[1]);
    }
}

// ---------------------------------------------------------------------------
// Per-(b,c) plane std of x, ddof=1. Two-stage deterministic reduction.
// ---------------------------------------------------------------------------
__global__ __launch_bounds__(256) void plane_std_part_k(
    const float* __restrict__ x, double* __restrict__ part) // [32][32][2]
{
    const int plane = blockIdx.x >> 5;       // 0..31
    const int blk   = blockIdx.x & 31;       // 0..31
    const float* p = x + (size_t)plane * 262144 + (size_t)blk * 8192;
    double s = 0.0, s2 = 0.0;
    for (int i = threadIdx.x; i < 2048; i += 256) {
        float4 v = ((const float4*)p)[i];
        s  += (double)v.x + (double)v.y + (double)v.z + (double)v.w;
        s2 += (double)v.x * v.x + (double)v.y * v.y
            + (double)v.z * v.z + (double)v.w * v.w;
    }
    __shared__ double ls[256], ls2[256];
    ls[threadIdx.x] = s; ls2[threadIdx.x] = s2;
    __syncthreads();
    for (int off = 128; off > 0; off >>= 1) {
        if (threadIdx.x < off) {
            ls[threadIdx.x]  += ls[threadIdx.x + off];
            ls2[threadIdx.x] += ls2[threadIdx.x + off];
        }
        __syncthreads();
    }
    if (threadIdx.x == 0) {
        part[2 * blockIdx.x]     = ls[0];
        part[2 * blockIdx.x + 1] = ls2[0];
    }
}

__global__ void plane_std_fin_k(const double* __restrict__ part,
                                float* __restrict__ stds)
{
    const int plane = threadIdx.x;
    if (plane >= 32) return;
    double s = 0.0, s2 = 0.0;
    for (int b = 0; b < 32; ++b) {
        s  += part[2 * (plane * 32 + b)];
        s2 += part[2 * (plane * 32 + b) + 1];
    }
    const double N = 262144.0;
    double var = (s2 - s * s / N) / (N - 1.0);
    stds[plane] = (float)sqrt(var > 0.0 ? var : 0.0);
}

// ---------------------------------------------------------------------------
// Exact quantile via 3-level radix histogram (12+12+8 bits) on the uint
// interpretation of the (non-negative) fused values. LDS sub-histograms;
// block-parallel rank select.
// ---------------------------------------------------------------------------
__global__ __launch_bounds__(256) void hist1_k(
    const float* __restrict__ fused, unsigned* __restrict__ h)
{
    __shared__ unsigned lh[4096];
    for (int i = threadIdx.x; i < 4096; i += 256) lh[i] = 0u;
    __syncthreads();
    const int base = blockIdx.x * 2048;
    for (int i = threadIdx.x; i < 2048; i += 256) {
        unsigned bits = __float_as_uint(fused[base + i]);
        atomicAdd(&lh[bits >> 20], 1u);
    }
    __syncthreads();
    for (int i = threadIdx.x; i < 4096; i += 256) {
        unsigned c = lh[i];
        if (c) atomicAdd(&h[i], c);
    }
}

// Parallel rank-select over a 4096-bin histogram. grid = 4 (one block per
// target). level 1: shared h1, rank = quantile targets, pfx = bin<<20.
// level 2: per-target h2 slice, rank = rem[tt], pfx |= bin<<8.
__global__ __launch_bounds__(256) void select_par_k(
    const unsigned* __restrict__ h, unsigned* __restrict__ pfx,
    unsigned* __restrict__ rem, int level)
{
    const int tt = blockIdx.x;
    const int t = threadIdx.x, lane = t & 63, wid = t >> 6;
    const unsigned targets[4] = {524287u, 524288u, 1572863u, 1572864u};
    const unsigned R = (level == 1) ? targets[tt] : rem[tt];
    const unsigned* hb = (level == 1) ? h : h + tt * 4096;

    unsigned loc[16], lsum = 0;
    const uint4* hv = (const uint4*)(hb + t * 16);
#pragma unroll
    for (int i = 0; i < 4; ++i) {
        uint4 v = hv[i];
        loc[4*i]=v.x; loc[4*i+1]=v.y; loc[4*i+2]=v.z; loc[4*i+3]=v.w;
        lsum += v.x + v.y + v.z + v.w;
    }
    // block exclusive scan of per-thread sums
    __shared__ unsigned warr[4];
    __shared__ unsigned rbin, rrem;
    unsigned inc = lsum;
#pragma unroll
    for (int off = 1; off < 64; off <<= 1) {
        unsigned up = __shfl_up(inc, (unsigned)off, 64);
        if (lane >= off) inc += up;
    }
    if (lane == 63) warr[wid] = inc;
    __syncthreads();
    unsigned wpre = 0;
#pragma unroll
    for (int w = 0; w < 4; ++w) if (w < wid) wpre += warr[w];
    unsigned ex = wpre + inc - lsum;
    // exactly one thread's disjoint interval [ex, ex+lsum) contains R
    if (R >= ex && R < ex + lsum) {
        unsigned cum = ex;
#pragma unroll
        for (int i = 0; i < 16; ++i) {
            if (cum + loc[i] > R) { rbin = (unsigned)(t * 16 + i); rrem = R - cum; break; }
            cum += loc[i];
        }
    }
    __syncthreads();
    if (t == 0) {
        if (level == 1) { pfx[tt] = rbin << 20; rem[tt] = rrem; }
        else            { pfx[tt] |= rbin << 8; rem[tt] = rrem; }
    }
}

// grid: 1024 blocks x 2048 elems. LDS [4][4096] = 64 KB sub-histograms.
__global__ __launch_bounds__(256) void hist2_k(
    const float* __restrict__ fused, const unsigned* __restrict__ pfx,
    unsigned* __restrict__ h2)
{
    __shared__ unsigned lh[4 * 4096];
    for (int i = threadIdx.x; i < 4 * 4096; i += 256) lh[i] = 0u;
    unsigned p0 = pfx[0] >> 20, p1 = pfx[1] >> 20,
             p2 = pfx[2] >> 20, p3 = pfx[3] >> 20;
    __syncthreads();
    const int base = blockIdx.x * 2048;
    for (int i = threadIdx.x; i < 2048; i += 256) {
        unsigned bits = __float_as_uint(fused[base + i]);
        unsigned top = bits >> 20;
        unsigned mid = (bits >> 8) & 0xFFFu;
        if (top == p0) atomicAdd(&lh[0 * 4096 + mid], 1u);
        if (top == p1) atomicAdd(&lh[1 * 4096 + mid], 1u);
        if (top == p2) atomicAdd(&lh[2 * 4096 + mid], 1u);
        if (top == p3) atomicAdd(&lh[3 * 4096 + mid], 1u);
    }
    __syncthreads();
    for (int i = threadIdx.x; i < 4 * 4096; i += 256) {
        unsigned c = lh[i];
        if (c) atomicAdd(&h2[i], c);
    }
}

// grid: 1024 blocks x 2048 elems. LDS [4][256] sub-histograms.
__global__ __launch_bounds__(256) void hist3_k(
    const float* __restrict__ fused, const unsigned* __restrict__ pfx,
    unsigned* __restrict__ h3)
{
    __shared__ unsigned lh[4 * 256];
    for (int i = threadIdx.x; i < 4 * 256; i += 256) lh[i] = 0u;
    unsigned p0 = pfx[0] >> 8, p1 = pfx[1] >> 8,
             p2 = pfx[2] >> 8, p3 = pfx[3] >> 8;
    __syncthreads();
    const int base = blockIdx.x * 2048;
    for (int i = threadIdx.x; i < 2048; i += 256) {
        unsigned bits = __float_as_uint(fused[base + i]);
        unsigned top = bits >> 8;
        unsigned low = bits & 0xFFu;
        if (top == p0) atomicAdd(&lh[0 * 256 + low], 1u);
        if (top == p1) atomicAdd(&lh[1 * 256 + low], 1u);
        if (top == p2) atomicAdd(&lh[2 * 256 + low], 1u);
        if (top == p3) atomicAdd(&lh[3 * 256 + low], 1u);
    }
    __syncthreads();
    for (int i = threadIdx.x; i < 4 * 256; i += 256) {
        unsigned c = lh[i];
        if (c) atomicAdd(&h3[i], c);
    }
}

__device__ __forceinline__ float clampf(float v, float lo, float hi) {
    return v < lo ? lo : (v > hi ? hi : v);
}

// Level-3 select (wave-parallel: 4 waves x 64 lanes x 4 bins) + scalar
// threshold math on thread 0.
__global__ __launch_bounds__(256) void finalize_k(
    const unsigned* __restrict__ h3,
    const unsigned* __restrict__ pfx,
    const unsigned* __restrict__ rem,
    const float* __restrict__ stds,
    const float* __restrict__ cw,
    float* __restrict__ lu)
{
    const int tt = threadIdx.x >> 6, lane = threadIdx.x & 63;
    __shared__ float vals[4];

    {
        const unsigned R = rem[tt];
        const unsigned* h = h3 + tt * 256;
        uint4 v = ((const uint4*)h)[lane];
        unsigned loc[4] = {v.x, v.y, v.z, v.w};
        unsigned lsum = v.x + v.y + v.z + v.w;
        unsigned inc = lsum;
#pragma unroll
        for (int off = 1; off < 64; off <<= 1) {
            unsigned up = __shfl_up(inc, (unsigned)off, 64);
            if (lane >= off) inc += up;
        }
        unsigned ex = inc - lsum;
        if (R >= ex && R < ex + lsum) {
            unsigned cum = ex;
#pragma unroll
            for (int i = 0; i < 4; ++i) {
                if (cum + loc[i] > R) {
                    vals[tt] = __uint_as_float(pfx[tt] | (unsigned)(lane * 4 + i));
                    break;
                }
                cum += loc[i];
            }
        }
    }
    __syncthreads();
    if (threadIdx.x != 0) return;

    float q25 = vals[0] + 0.75f * (vals[1] - vals[0]);
    float q75 = vals[2] + 0.25f * (vals[3] - vals[2]);
    float iqr = q75 - q25;
    if (iqr < 1e-5f) iqr = 0.05f;
    float lo0 = q25 - 0.5f * iqr, up0 = q75 + 0.5f * iqr;

    // softmax over channel_weights (4)
    float mx = cw[0];
    for (int c = 1; c < 4; ++c) mx = cw[c] > mx ? cw[c] : mx;
    float e[4], se = 0.f;
    for (int c = 0; c < 4; ++c) { e[c] = expf(cw[c] - mx); se += e[c]; }

    float l[32], u[32], mind = 1e30f;
    for (int p = 0; p < 32; ++p) {
        float sd = stds[p];
        int c = p & 3;
        float gf = clampf(sd * 5.f, 0.5f, 2.f);
        float cf = clampf(sd * (e[c] / se) * 2.f, 0.8f, 1.2f);
        l[p] = lo0 * gf * cf;
        u[p] = up0 * gf * cf;
        float d = fabsf(u[p] - l[p]);
        if (d < mind) mind = d;
    }
    bool deg = mind < 1e-5f;
    for (int p = 0; p < 32; ++p) {
        float L = l[p], U = u[p];
        if (deg) { float m = 0.5f * (L + U); L = m - 0.05f; U = m + 0.05f; }
        lu[p] = L; lu[32 + p] = U;
    }
}

__global__ __launch_bounds__(256) void mask_k(
    const float* __restrict__ fused, const float* __restrict__ lu,
    float* __restrict__ out)
{
    const int b = blockIdx.y;
    const int i = blockIdx.x * 256 + threadIdx.x;
    float fv = fused[(size_t)b * 262144 + i];
    float s = 0.f;
#pragma unroll
    for (int c = 0; c < 4; ++c) {
        float L = lu[b * 4 + c], U = lu[32 + b * 4 + c];
        float d = U - L; d = d > 1e-5f ? d : 1e-5f;
        float n = (fv - L) / d;
        n = n < 0.f ? 0.f : (n > 1.f ? 1.f : n);
        s += 1.f / (1.f + expf(3.f - 6.f * n));
    }
    out[(size_t)b * 262144 + i] = 0.25f * s;
}

// ---------------------------------------------------------------------------
extern "C" void kernel_launch(void* const* d_in, const int* in_sizes, int n_in,
                              void* d_out, int out_size, void* d_ws, size_t ws_size,
                              hipStream_t stream)
{
    const float* x   = (const float*)d_in[0];
    const float* c1w = (const float*)d_in[1];
    const float* c1b = (const float*)d_in[2];
    const float* c2w = (const float*)d_in[3];
    const float* c2b = (const float*)d_in[4];
    const float* c3w = (const float*)d_in[5];
    const float* c3b = (const float*)d_in[6];
    const float* fw  = (const float*)d_in[7];
    const float* fb  = (const float*)d_in[8];
    const float* cwt = (const float*)d_in[9];
    float* out = (float*)d_out;
    char* ws = (char*)d_ws;

    const size_t PLANE = 512 * 512;

    // ws layout: fused | stds | lu | pfx | rem | h1|h2|h3 | partials | chunk
    float* fused = (float*)ws;
    size_t off = 8 * PLANE * sizeof(float);
    float* stds = (float*)(ws + off); off += 32 * 4;
    float* lu   = (float*)(ws + off); off += 64 * 4;
    off = (off + 255) & ~(size_t)255;
    unsigned* pfx = (unsigned*)(ws + off); off += 16;
    unsigned* rem = (unsigned*)(ws + off); off += 16;
    off = (off + 255) & ~(size_t)255;
    unsigned* h1 = (unsigned*)(ws + off); off += 4096 * 4;
    unsigned* h2 = (unsigned*)(ws + off); off += 4 * 4096 * 4;
    unsigned* h3 = (unsigned*)(ws + off); off += 4 * 256 * 4;
    off = (off + 255) & ~(size_t)255;
    double* part = (double*)(ws + off); off += 1024 * 2 * sizeof(double);
    off = (off + 1023) & ~(size_t)1023;

    // chunk buffers: f1(32ch) + f2(16ch) + f(8ch) per batch = 56 planes
    const size_t perb = 56 * PLANE * sizeof(float);
    int nb = 8;
    while (nb > 1 && off + (size_t)nb * perb > ws_size) nb >>= 1;
    float* f1  = (float*)(ws + off);
    float* f2  = f1 + (size_t)nb * 32 * PLANE;
    float* fch = f2 + (size_t)nb * 16 * PLANE;

    hipLaunchKernelGGL(plane_std_part_k, dim3(1024), dim3(256), 0, stream, x, part);
    hipLaunchKernelGGL(plane_std_fin_k,  dim3(1),    dim3(64),  0, stream, part, stds);

    for (int b0 = 0; b0 < 8; b0 += nb) {
        const float* xc = x + (size_t)b0 * 4 * PLANE;
        hipLaunchKernelGGL((conv3x3_k<4, 32, 8, true>),   dim3(8, 16, nb * 4),
                           dim3(256), 0, stream, xc, c1w, c1b, f1);
        hipLaunchKernelGGL((conv3x3_k<32, 16, 16, true>), dim3(8, 16, nb),
                           dim3(256), 0, stream, f1, c2w, c2b, f2);
        hipLaunchKernelGGL((conv3x3_k<16, 8, 8, false>),  dim3(8, 16, nb),
                           dim3(256), 0, stream, f2, c3w, c3b, fch);
        hipLaunchKernelGGL(stdmap_k, dim3(512 / YB, nb), dim3(256), 0, stream,
                           fch, fw, fb, fused, b0);
    }

    hipMemsetAsync(h1, 0, (4096 + 4 * 4096 + 4 * 256) * 4, stream);
    hipLaunchKernelGGL(hist1_k,     dim3(1024), dim3(256), 0, stream, fused, h1);
    hipLaunchKernelGGL(select_par_k, dim3(4),   dim3(256), 0, stream, h1, pfx, rem, 1);
    hipLaunchKernelGGL(hist2_k,     dim3(1024), dim3(256), 0, stream, fused, pfx, h2);
    hipLaunchKernelGGL(select_par_k, dim3(4),   dim3(256), 0, stream, h2, pfx, rem, 2);
    hipLaunchKernelGGL(hist3_k,     dim3(1024), dim3(256), 0, stream, fused, pfx, h3);
    hipLaunchKernelGGL(finalize_k,  dim3(1),    dim3(256), 0, stream,
                       h3, pfx, rem, stds, cwt, lu);
    hipLaunchKernelGGL(mask_k, dim3(1024, 8), dim3(256), 0, stream, fused, lu, out);
}